// Round 1
// baseline (429.597 us; speedup 1.0000x reference)
//
#include <hip/hip_runtime.h>
#include <cstdint>
#include <cstddef>

using short8 = __attribute__((ext_vector_type(8))) short;
using f32x4  = __attribute__((ext_vector_type(4))) float;
typedef unsigned short u16;

__device__ __forceinline__ u16 f2bf(float f) {
    uint32_t u = __builtin_bit_cast(uint32_t, f);
    u += 0x7fffu + ((u >> 16) & 1u);
    return (u16)(u >> 16);
}

// ---------------------------------------------------------------------------
// GEMM: C[M][N] = A[M][K] * Bw[N][K]^T   (A fp32 or bf16(u16), Bw fp32, C fp32)
// 64x64 tile, BK=64, 4 waves (2x2), each wave 32x32 via 2x2 16x16x32 MFMA frags
// ---------------------------------------------------------------------------
template<int ABF16>
__global__ __launch_bounds__(256) void gemm_bt_kernel(const void* __restrict__ Ap,
                                                      const float* __restrict__ Bw,
                                                      float* __restrict__ C,
                                                      int M, int N, int K)
{
    __shared__ __align__(16) u16 As[64][72];
    __shared__ __align__(16) u16 Bs[64][72];

    const int tid  = threadIdx.x;
    const int lane = tid & 63;
    const int w    = tid >> 6;
    const int wr   = w >> 1, wc = w & 1;
    const int l15  = lane & 15;
    const int lg   = lane >> 4;
    const int strow = tid >> 2;        // 0..63
    const int stc0  = (tid & 3) * 16;  // 0,16,32,48
    const int rowA = blockIdx.y * 64;
    const int colB = blockIdx.x * 64;

    f32x4 acc[2][2] = {};
    const int nkt = K / 64;
    for (int kt = 0; kt < nkt; ++kt) {
        __syncthreads();
        // stage A tile (convert to bf16 if fp32)
        {
            size_t off = (size_t)(rowA + strow) * K + (size_t)kt * 64 + stc0;
            u16 tmp[16];
            if (ABF16) {
                const short8* s = reinterpret_cast<const short8*>((const u16*)Ap + off);
                short8 v0 = s[0], v1 = s[1];
#pragma unroll
                for (int e = 0; e < 8; e++) { tmp[e] = (u16)v0[e]; tmp[8 + e] = (u16)v1[e]; }
            } else {
                const float4* s = reinterpret_cast<const float4*>((const float*)Ap + off);
#pragma unroll
                for (int q2 = 0; q2 < 4; q2++) {
                    float4 v = s[q2];
                    tmp[4*q2+0] = f2bf(v.x); tmp[4*q2+1] = f2bf(v.y);
                    tmp[4*q2+2] = f2bf(v.z); tmp[4*q2+3] = f2bf(v.w);
                }
            }
            short8 t0, t1;
#pragma unroll
            for (int e = 0; e < 8; e++) { t0[e] = (short)tmp[e]; t1[e] = (short)tmp[8 + e]; }
            *reinterpret_cast<short8*>(&As[strow][stc0])     = t0;
            *reinterpret_cast<short8*>(&As[strow][stc0 + 8]) = t1;
        }
        // stage B tile (weights fp32 -> bf16)
        {
            size_t off = (size_t)(colB + strow) * K + (size_t)kt * 64 + stc0;
            const float4* s = reinterpret_cast<const float4*>(Bw + off);
            u16 tmp[16];
#pragma unroll
            for (int q2 = 0; q2 < 4; q2++) {
                float4 v = s[q2];
                tmp[4*q2+0] = f2bf(v.x); tmp[4*q2+1] = f2bf(v.y);
                tmp[4*q2+2] = f2bf(v.z); tmp[4*q2+3] = f2bf(v.w);
            }
            short8 t0, t1;
#pragma unroll
            for (int e = 0; e < 8; e++) { t0[e] = (short)tmp[e]; t1[e] = (short)tmp[8 + e]; }
            *reinterpret_cast<short8*>(&Bs[strow][stc0])     = t0;
            *reinterpret_cast<short8*>(&Bs[strow][stc0 + 8]) = t1;
        }
        __syncthreads();

#pragma unroll
        for (int c = 0; c < 2; c++) {
            short8 af[2], bf[2];
#pragma unroll
            for (int mi = 0; mi < 2; mi++)
                af[mi] = *reinterpret_cast<const short8*>(&As[wr*32 + mi*16 + l15][c*32 + 8*lg]);
#pragma unroll
            for (int ni = 0; ni < 2; ni++)
                bf[ni] = *reinterpret_cast<const short8*>(&Bs[wc*32 + ni*16 + l15][c*32 + 8*lg]);
#pragma unroll
            for (int mi = 0; mi < 2; mi++)
#pragma unroll
                for (int ni = 0; ni < 2; ni++)
                    acc[mi][ni] = __builtin_amdgcn_mfma_f32_16x16x32_bf16(af[mi], bf[ni], acc[mi][ni], 0, 0, 0);
        }
    }

#pragma unroll
    for (int mi = 0; mi < 2; mi++)
#pragma unroll
        for (int ni = 0; ni < 2; ni++)
#pragma unroll
            for (int rr = 0; rr < 4; rr++) {
                int row = rowA + wr*32 + mi*16 + lg*4 + rr;
                int col = colB + wc*32 + ni*16 + l15;
                C[(size_t)row * N + col] = acc[mi][ni][rr];
            }
}

// ---------------------------------------------------------------------------
// Post-projection: cast fp32 -> bf16 (same [B*N, D] layout) + per-(b,h,n) norms
// one wave per (row, head) slice of 64
// ---------------------------------------------------------------------------
__global__ __launch_bounds__(256) void postproj_kernel(const float* __restrict__ f,
                                                       u16* __restrict__ bfo,
                                                       float* __restrict__ norms)
{
    constexpr int Nq = 2048, Dm = 1024, Hh = 16;
    int gw   = blockIdx.x * 4 + (threadIdx.x >> 6);
    int lane = threadIdx.x & 63;
    int row  = gw >> 4;   // 0 .. B*N-1
    int h    = gw & 15;
    size_t idx = (size_t)row * Dm + h * 64 + lane;
    float v = f[idx];
    bfo[idx] = f2bf(v);
    float s = v * v;
#pragma unroll
    for (int m = 1; m < 64; m <<= 1) s += __shfl_xor(s, m);
    if (lane == 0) {
        int b = row / Nq;
        int n = row % Nq;
        norms[((size_t)(b * Hh + h)) * Nq + n] = s;
    }
}

// ---------------------------------------------------------------------------
// Fused causal hyperbolic flash attention.
// Block: 256 thr (4 waves). Q tile 64 rows (16 per wave). KV tiles of 64.
// ---------------------------------------------------------------------------
__global__ __launch_bounds__(256) void hypattn_kernel(
    const u16* __restrict__ qb, const u16* __restrict__ kb, const u16* __restrict__ vb,
    const float* __restrict__ qn, const float* __restrict__ kn,
    u16* __restrict__ ob, const float* __restrict__ log_c, const float* __restrict__ log_beta)
{
    constexpr int Nq = 2048, Dm = 1024, Dh = 64;
    __shared__ __align__(16) u16 Ks[64][72];
    __shared__ __align__(16) u16 Vt[64][72];
    __shared__ __align__(16) u16 Pw[4][16][72];

    const int tid   = threadIdx.x;
    const int lane  = tid & 63;
    const int w     = tid >> 6;
    const int qtile = blockIdx.x;
    const int bh    = blockIdx.y;
    const int b     = bh >> 4;
    const int h     = bh & 15;
    const int l15   = lane & 15;
    const int lg    = lane >> 4;
    const int strow = tid >> 2;
    const int stc0  = (tid & 3) * 16;

    const float c    = log1pf(expf(log_c[0]));
    const float beta = log1pf(expf(log_beta[0])) + 0.5f;

    // Q fragments (held for the whole kernel)
    short8 qf[2];
    {
        int n = qtile * 64 + w * 16 + l15;
        size_t base = ((size_t)(b * Nq + n)) * Dm + h * Dh;
#pragma unroll
        for (int cch = 0; cch < 2; cch++)
            qf[cch] = *reinterpret_cast<const short8*>(qb + base + cch * 32 + 8 * lg);
    }
    float qnr[4];
#pragma unroll
    for (int rr = 0; rr < 4; rr++)
        qnr[rr] = qn[(size_t)bh * Nq + qtile * 64 + w * 16 + lg * 4 + rr];

    float mrow[4], lrow[4];
#pragma unroll
    for (int rr = 0; rr < 4; rr++) { mrow[rr] = -INFINITY; lrow[rr] = 0.f; }
    f32x4 oacc[4] = {};

    for (int t = 0; t <= qtile; ++t) {
        __syncthreads();
        // stage K tile and transposed V tile
        {
            size_t off = ((size_t)(b * Nq + t * 64 + strow)) * Dm + h * Dh + stc0;
            const short8* sk = reinterpret_cast<const short8*>(kb + off);
            *reinterpret_cast<short8*>(&Ks[strow][stc0])     = sk[0];
            *reinterpret_cast<short8*>(&Ks[strow][stc0 + 8]) = sk[1];
            const short8* sv = reinterpret_cast<const short8*>(vb + off);
            short8 v0 = sv[0], v1 = sv[1];
#pragma unroll
            for (int e = 0; e < 8; e++) {
                Vt[stc0 + e][strow]     = (u16)v0[e];
                Vt[stc0 + 8 + e][strow] = (u16)v1[e];
            }
        }
        __syncthreads();

        float knj[4];
#pragma unroll
        for (int nt = 0; nt < 4; nt++)
            knj[nt] = kn[(size_t)bh * Nq + t * 64 + nt * 16 + l15];

        f32x4 sacc[4] = {};
#pragma unroll
        for (int cch = 0; cch < 2; cch++) {
#pragma unroll
            for (int nt = 0; nt < 4; nt++) {
                short8 kf = *reinterpret_cast<const short8*>(&Ks[nt*16 + l15][cch*32 + 8*lg]);
                sacc[nt] = __builtin_amdgcn_mfma_f32_16x16x32_bf16(qf[cch], kf, sacc[nt], 0, 0, 0);
            }
        }

        // hyperbolic distance -> scores, causal mask, online softmax
        float p[4][4];
        float tmax[4];
#pragma unroll
        for (int rr = 0; rr < 4; rr++) tmax[rr] = -INFINITY;
#pragma unroll
        for (int nt = 0; nt < 4; nt++) {
#pragma unroll
            for (int rr = 0; rr < 4; rr++) {
                float qk  = sacc[nt][rr];
                float qnv = qnr[rr];
                float knv = knj[nt];
                float d2  = fmaxf(qnv - 2.f * qk + knv, 0.f);
                float ed  = sqrtf(d2 + 1e-8f);
                float ns  = qnv + knv;
                float cn  = c * ns;
                float dist;
                if (ed < 0.1f)      dist = ed * (1.f + cn * 0.5f + cn * cn * 0.125f);
                else if (ed > 2.f)  dist = 0.693f + logf(ed + 1e-8f) + cn * 0.25f;
                else                dist = ed * sqrtf(1.f + cn);
                float sc = -beta * dist;
                int kcol = t * 64 + nt * 16 + l15;
                int qrow = qtile * 64 + w * 16 + lg * 4 + rr;
                if (kcol > qrow) sc = -INFINITY;
                p[nt][rr] = sc;
                tmax[rr]  = fmaxf(tmax[rr], sc);
            }
        }
#pragma unroll
        for (int rr = 0; rr < 4; rr++) {
#pragma unroll
            for (int mk = 1; mk < 16; mk <<= 1)
                tmax[rr] = fmaxf(tmax[rr], __shfl_xor(tmax[rr], mk));
        }
        float ssum[4];
#pragma unroll
        for (int rr = 0; rr < 4; rr++) {
            float mnew  = fmaxf(mrow[rr], tmax[rr]);
            float scale = expf(mrow[rr] - mnew);
            float s = 0.f;
#pragma unroll
            for (int nt = 0; nt < 4; nt++) {
                float pv = expf(p[nt][rr] - mnew);
                p[nt][rr] = pv;
                s += pv;
            }
            ssum[rr] = s;
            mrow[rr] = mnew;
            lrow[rr] *= scale;
#pragma unroll
            for (int no = 0; no < 4; no++) oacc[no][rr] *= scale;
        }
#pragma unroll
        for (int rr = 0; rr < 4; rr++) {
#pragma unroll
            for (int mk = 1; mk < 16; mk <<= 1)
                ssum[rr] += __shfl_xor(ssum[rr], mk);
            lrow[rr] += ssum[rr];
        }
        // write P (bf16) to per-wave LDS, re-read as A-fragments
#pragma unroll
        for (int nt = 0; nt < 4; nt++)
#pragma unroll
            for (int rr = 0; rr < 4; rr++)
                Pw[w][lg * 4 + rr][nt * 16 + l15] = f2bf(p[nt][rr]);

#pragma unroll
        for (int cch = 0; cch < 2; cch++) {
            short8 pf = *reinterpret_cast<const short8*>(&Pw[w][l15][cch*32 + 8*lg]);
#pragma unroll
            for (int no = 0; no < 4; no++) {
                short8 vf = *reinterpret_cast<const short8*>(&Vt[no*16 + l15][cch*32 + 8*lg]);
                oacc[no] = __builtin_amdgcn_mfma_f32_16x16x32_bf16(pf, vf, oacc[no], 0, 0, 0);
            }
        }
    }

    // epilogue: normalize and store bf16 [B*N, D]
#pragma unroll
    for (int no = 0; no < 4; no++)
#pragma unroll
        for (int rr = 0; rr < 4; rr++) {
            int n   = qtile * 64 + w * 16 + lg * 4 + rr;
            int col = h * Dh + no * 16 + l15;
            float val = oacc[no][rr] / lrow[rr];
            ob[((size_t)(b * Nq + n)) * Dm + col] = f2bf(val);
        }
}

// ---------------------------------------------------------------------------
extern "C" void kernel_launch(void* const* d_in, const int* in_sizes, int n_in,
                              void* d_out, int out_size, void* d_ws, size_t ws_size,
                              hipStream_t stream)
{
    const float* x        = (const float*)d_in[0];
    const float* Wq       = (const float*)d_in[1];
    const float* Wk       = (const float*)d_in[2];
    const float* Wv       = (const float*)d_in[3];
    const float* Wo       = (const float*)d_in[4];
    const float* log_c    = (const float*)d_in[5];
    const float* log_beta = (const float*)d_in[6];
    float* out = (float*)d_out;

    constexpr int B = 2, N = 2048, D = 1024, H = 16;
    constexpr size_t ROWS = (size_t)B * N;       // 4096
    char* ws = (char*)d_ws;
    float* tmpf = (float*)ws;                     // ROWS*D fp32 (reused q/k/v)
    u16* qb = (u16*)(ws + (size_t)ROWS * D * 4);
    u16* kb = qb + ROWS * D;
    u16* vb = kb + ROWS * D;
    u16* ob = vb + ROWS * D;
    float* qn = (float*)(ob + ROWS * D);
    float* kn = qn + (size_t)B * H * N;
    float* vn = kn + (size_t)B * H * N;

    dim3 gg(D / 64, ROWS / 64);       // (16, 64)
    dim3 ga(N / 64, B * H);           // (32, 32)
    const int npp = (B * N * H) / 4;  // postproj blocks

    gemm_bt_kernel<0><<<gg, 256, 0, stream>>>(x, Wq, tmpf, (int)ROWS, D, D);
    postproj_kernel<<<npp, 256, 0, stream>>>(tmpf, qb, qn);
    gemm_bt_kernel<0><<<gg, 256, 0, stream>>>(x, Wk, tmpf, (int)ROWS, D, D);
    postproj_kernel<<<npp, 256, 0, stream>>>(tmpf, kb, kn);
    gemm_bt_kernel<0><<<gg, 256, 0, stream>>>(x, Wv, tmpf, (int)ROWS, D, D);
    postproj_kernel<<<npp, 256, 0, stream>>>(tmpf, vb, vn);
    hypattn_kernel<<<ga, 256, 0, stream>>>(qb, kb, vb, qn, kn, ob, log_c, log_beta);
    gemm_bt_kernel<1><<<gg, 256, 0, stream>>>(ob, Wo, out, (int)ROWS, D, D);
}

// Round 2
// 254.419 us; speedup vs baseline: 1.6885x; 1.6885x over previous
//
#include <hip/hip_runtime.h>
#include <cstdint>
#include <cstddef>

using short8 = __attribute__((ext_vector_type(8))) short;
using f32x4  = __attribute__((ext_vector_type(4))) float;
typedef unsigned short u16;
typedef unsigned int   u32;

__device__ __forceinline__ u16 f2bf(float f) {
    uint32_t u = __builtin_bit_cast(uint32_t, f);
    u += 0x7fffu + ((u >> 16) & 1u);
    return (u16)(u >> 16);
}

__device__ __forceinline__ void gload_lds16(const u16* g, u16* l) {
    __builtin_amdgcn_global_load_lds(
        (const __attribute__((address_space(1))) u32*)g,
        (__attribute__((address_space(3))) u32*)l, 16, 0, 0);
}

// ---------------------------------------------------------------------------
// fp32 -> bf16 cast of x (4M elems) and Wq/Wk/Wv/Wo (1M each)
// ---------------------------------------------------------------------------
__global__ __launch_bounds__(256) void castx_kernel(
    const float* __restrict__ x,  const float* __restrict__ wq,
    const float* __restrict__ wk, const float* __restrict__ wv,
    const float* __restrict__ wo,
    u16* __restrict__ xb,  u16* __restrict__ wqb, u16* __restrict__ wkb,
    u16* __restrict__ wvb, u16* __restrict__ wob)
{
    size_t i = ((size_t)blockIdx.x * 256 + threadIdx.x) * 8;
    const float* src; u16* dst; size_t off;
    if (i < (size_t)(4u << 20)) { src = x; dst = xb; off = i; }
    else {
        size_t j = i - (size_t)(4u << 20);
        int sel = (int)(j >> 20);
        off = j & (((size_t)1 << 20) - 1);
        src = sel == 0 ? wq : sel == 1 ? wk : sel == 2 ? wv : wo;
        dst = sel == 0 ? wqb : sel == 1 ? wkb : sel == 2 ? wvb : wob;
    }
    float4 a = *reinterpret_cast<const float4*>(src + off);
    float4 b = *reinterpret_cast<const float4*>(src + off + 4);
    short8 o;
    o[0] = (short)f2bf(a.x); o[1] = (short)f2bf(a.y);
    o[2] = (short)f2bf(a.z); o[3] = (short)f2bf(a.w);
    o[4] = (short)f2bf(b.x); o[5] = (short)f2bf(b.y);
    o[6] = (short)f2bf(b.z); o[7] = (short)f2bf(b.w);
    *reinterpret_cast<short8*>(dst + off) = o;
}

// ---------------------------------------------------------------------------
// m97-style GEMM core: 128x128 tile, BK=64, global_load_lds width 16.
// C = A[M][K] * B[N][K]^T, A/B bf16. K=1024 (16 K-steps).
// ---------------------------------------------------------------------------
__device__ __forceinline__ void gemm_core(const u16* __restrict__ A,
                                          const u16* __restrict__ Bw,
                                          u16* As, u16* Bs,
                                          int rowA, int colB,
                                          f32x4 acc[4][4])
{
    const int tid = threadIdx.x, lane = tid & 63, w = tid >> 6;
    const int l15 = lane & 15, lg = lane >> 4;
    const int wr = w >> 1, wc = w & 1;
    const int srow = lane >> 3, scol = (lane & 7) * 8;
    constexpr int K = 1024;

    for (int kt = 0; kt < 16; ++kt) {
        __syncthreads();
#pragma unroll
        for (int i = 0; i < 4; i++) {
            int r = w * 32 + i * 8;
            gload_lds16(A  + (size_t)(rowA + r + srow) * K + kt * 64 + scol, As + r * 64);
            gload_lds16(Bw + (size_t)(colB + r + srow) * K + kt * 64 + scol, Bs + r * 64);
        }
        __syncthreads();
#pragma unroll
        for (int c = 0; c < 2; c++) {
            short8 af[4], bf[4];
#pragma unroll
            for (int mi = 0; mi < 4; mi++)
                af[mi] = *reinterpret_cast<const short8*>(As + (wr*64 + mi*16 + l15)*64 + c*32 + 8*lg);
#pragma unroll
            for (int ni = 0; ni < 4; ni++)
                bf[ni] = *reinterpret_cast<const short8*>(Bs + (wc*64 + ni*16 + l15)*64 + c*32 + 8*lg);
#pragma unroll
            for (int mi = 0; mi < 4; mi++)
#pragma unroll
                for (int ni = 0; ni < 4; ni++)
                    acc[mi][ni] = __builtin_amdgcn_mfma_f32_16x16x32_bf16(af[mi], bf[ni], acc[mi][ni], 0, 0, 0);
        }
    }
}

// QKV fused: grid (8, 32, 3). Writes bf16 q/k/v + fp32 row-norms for q,k.
__global__ __launch_bounds__(256) void gemm_qkv_kernel(
    const u16* __restrict__ xb,
    const u16* __restrict__ w0, const u16* __restrict__ w1, const u16* __restrict__ w2,
    u16* __restrict__ c0, u16* __restrict__ c1, u16* __restrict__ c2,
    float* __restrict__ qn, float* __restrict__ kn)
{
    __shared__ __align__(16) u16 As[128 * 64];
    __shared__ __align__(16) u16 Bs[128 * 64];
    const int z = blockIdx.z;
    const u16* W = z == 0 ? w0 : (z == 1 ? w1 : w2);
    u16* C       = z == 0 ? c0 : (z == 1 ? c1 : c2);
    float* nrm   = z == 0 ? qn : (z == 1 ? kn : nullptr);
    const int rowA = blockIdx.y * 128, colB = blockIdx.x * 128;

    f32x4 acc[4][4] = {};
    gemm_core(xb, W, As, Bs, rowA, colB, acc);

    const int tid = threadIdx.x, lane = tid & 63, w = tid >> 6;
    const int l15 = lane & 15, lg = lane >> 4;
    const int wr = w >> 1, wc = w & 1;
#pragma unroll
    for (int mi = 0; mi < 4; mi++)
#pragma unroll
        for (int ni = 0; ni < 4; ni++)
#pragma unroll
            for (int rr = 0; rr < 4; rr++) {
                int row = rowA + wr*64 + mi*16 + lg*4 + rr;
                int col = colB + wc*64 + ni*16 + l15;
                C[(size_t)row * 1024 + col] = f2bf(acc[mi][ni][rr]);
            }
    if (nrm) {
        int hh = blockIdx.x * 2 + wc;
#pragma unroll
        for (int mi = 0; mi < 4; mi++)
#pragma unroll
            for (int rr = 0; rr < 4; rr++) {
                float s = 0.f;
#pragma unroll
                for (int ni = 0; ni < 4; ni++) { float v = acc[mi][ni][rr]; s += v * v; }
#pragma unroll
                for (int m = 1; m < 16; m <<= 1) s += __shfl_xor(s, m);
                if (l15 == 0) {
                    int row = rowA + wr*64 + mi*16 + lg*4 + rr;
                    nrm[((size_t)(row >> 11) * 16 + hh) * 2048 + (row & 2047)] = s;
                }
            }
    }
}

// Final projection: fp32 out. grid (8, 32).
__global__ __launch_bounds__(256) void gemm_out_kernel(
    const u16* __restrict__ ob, const u16* __restrict__ wob, float* __restrict__ out)
{
    __shared__ __align__(16) u16 As[128 * 64];
    __shared__ __align__(16) u16 Bs[128 * 64];
    const int rowA = blockIdx.y * 128, colB = blockIdx.x * 128;
    f32x4 acc[4][4] = {};
    gemm_core(ob, wob, As, Bs, rowA, colB, acc);
    const int tid = threadIdx.x, lane = tid & 63, w = tid >> 6;
    const int l15 = lane & 15, lg = lane >> 4;
    const int wr = w >> 1, wc = w & 1;
#pragma unroll
    for (int mi = 0; mi < 4; mi++)
#pragma unroll
        for (int ni = 0; ni < 4; ni++)
#pragma unroll
            for (int rr = 0; rr < 4; rr++) {
                int row = rowA + wr*64 + mi*16 + lg*4 + rr;
                int col = colB + wc*64 + ni*16 + l15;
                out[(size_t)row * 1024 + col] = acc[mi][ni][rr];
            }
}

// ---------------------------------------------------------------------------
// V transpose: vb [B*N][D] -> vt [(b*16+h)*64+d][N]  (bf16)
// grid 1024 = 32 bh * 32 ntile, 256 threads
// ---------------------------------------------------------------------------
__global__ __launch_bounds__(256) void transpose_v_kernel(const u16* __restrict__ vb,
                                                          u16* __restrict__ vt)
{
    __shared__ __align__(16) u16 T[64][80];
    const int bid = blockIdx.x;
    const int bh = bid >> 5, tile = bid & 31;
    const int b = bh >> 4, h = bh & 15;
#pragma unroll
    for (int i = 0; i < 2; i++) {
        int flat = threadIdx.x + i * 256;      // 0..511
        int r = flat >> 3, c8 = (flat & 7) * 8;
        short8 v = *reinterpret_cast<const short8*>(
            vb + (size_t)(b * 2048 + tile * 64 + r) * 1024 + h * 64 + c8);
#pragma unroll
        for (int e = 0; e < 8; e++) T[c8 + e][r] = (u16)v[e];
    }
    __syncthreads();
#pragma unroll
    for (int i = 0; i < 2; i++) {
        int flat = threadIdx.x + i * 256;
        int d = flat >> 3, c8 = (flat & 7) * 8;
        short8 v = *reinterpret_cast<const short8*>(&T[d][c8]);
        *reinterpret_cast<short8*>(vt + ((size_t)bh * 64 + d) * 2048 + tile * 64 + c8) = v;
    }
}

// ---------------------------------------------------------------------------
// Fused causal hyperbolic flash attention — 1 independent wave per 16 Q rows.
// grid 2048 blocks x 128 thr (2 waves/block). No __syncthreads. K/V from L2.
// ---------------------------------------------------------------------------
__global__ __launch_bounds__(128) void hypattn_kernel(
    const u16* __restrict__ qb, const u16* __restrict__ kb, const u16* __restrict__ vt,
    const float* __restrict__ qnp, const float* __restrict__ knp,
    u16* __restrict__ ob, const float* __restrict__ log_c, const float* __restrict__ log_beta)
{
    __shared__ __align__(16) u16 Pw[2][16][80];

    const int w    = threadIdx.x >> 6;
    const int lane = threadIdx.x & 63;
    const int l15  = lane & 15;
    const int lg   = lane >> 4;

    // XCD-chunked swizzle + big-tiles-first
    const int swz = (blockIdx.x & 7) * 256 + (blockIdx.x >> 3);
    const int wt  = 4095 - (swz * 2 + w);
    const int bh  = wt >> 7;
    const int j   = wt & 127;
    const int b   = bh >> 4, h = bh & 15;
    const int n0  = j * 16;
    const int ntiles = (j >> 2) + 1;

    const float cc   = log1pf(__expf(log_c[0]));
    const float beta = log1pf(__expf(log_beta[0])) + 0.5f;

    short8 qf[2];
    {
        size_t base = ((size_t)(b * 2048 + n0 + l15)) * 1024 + h * 64;
#pragma unroll
        for (int cch = 0; cch < 2; cch++)
            qf[cch] = *reinterpret_cast<const short8*>(qb + base + cch * 32 + 8 * lg);
    }
    float qnr[4];
#pragma unroll
    for (int rr = 0; rr < 4; rr++)
        qnr[rr] = qnp[(size_t)bh * 2048 + n0 + lg * 4 + rr];

    float mrow[4], lrow[4];
#pragma unroll
    for (int rr = 0; rr < 4; rr++) { mrow[rr] = -INFINITY; lrow[rr] = 0.f; }
    f32x4 oacc[4] = {};

    const u16* kbh = kb + (size_t)b * 2048 * 1024 + h * 64;
    const u16* vbh = vt + (size_t)bh * 64 * 2048;
    const float* knb = knp + (size_t)bh * 2048;

    for (int t = 0; t < ntiles; ++t) {
        // --- QK^T ---
        f32x4 sacc[4] = {};
        {
            const u16* kt0 = kbh + (size_t)(t * 64) * 1024;
#pragma unroll
            for (int cch = 0; cch < 2; cch++)
#pragma unroll
                for (int nt = 0; nt < 4; nt++) {
                    short8 kf = *reinterpret_cast<const short8*>(
                        kt0 + (size_t)(nt * 16 + l15) * 1024 + cch * 32 + 8 * lg);
                    sacc[nt] = __builtin_amdgcn_mfma_f32_16x16x32_bf16(qf[cch], kf, sacc[nt], 0, 0, 0);
                }
        }
        float knj[4];
#pragma unroll
        for (int nt = 0; nt < 4; nt++) knj[nt] = knb[t * 64 + nt * 16 + l15];

        const bool lastt = (t == ntiles - 1);
        float p[4][4];
        float tmax[4];
#pragma unroll
        for (int rr = 0; rr < 4; rr++) tmax[rr] = -INFINITY;
#pragma unroll
        for (int nt = 0; nt < 4; nt++)
#pragma unroll
            for (int rr = 0; rr < 4; rr++) {
                float qk = sacc[nt][rr];
                float nsq = qnr[rr], nsk = knj[nt];
                float d2 = fmaxf(nsq + nsk - 2.f * qk, 0.f);
                float ed = __builtin_amdgcn_sqrtf(d2 + 1e-8f);
                float cn = cc * (nsq + nsk);
                float dasym = 0.693f + 0.69314718f * __builtin_amdgcn_logf(ed + 1e-8f) + 0.25f * cn;
                float dstd  = ed * __builtin_amdgcn_sqrtf(1.f + cn);
                float dtay  = ed * (1.f + 0.5f * cn + 0.125f * cn * cn);
                float dist  = ed > 2.f ? dasym : (ed < 0.1f ? dtay : dstd);
                float sc = -beta * dist;
                if (lastt) {
                    int kcol = t * 64 + nt * 16 + l15;
                    int qrow = n0 + lg * 4 + rr;
                    if (kcol > qrow) sc = -INFINITY;
                }
                p[nt][rr] = sc;
                tmax[rr] = fmaxf(tmax[rr], sc);
            }
#pragma unroll
        for (int rr = 0; rr < 4; rr++) {
#pragma unroll
            for (int m = 1; m < 16; m <<= 1)
                tmax[rr] = fmaxf(tmax[rr], __shfl_xor(tmax[rr], m));
        }
        float ssum[4];
#pragma unroll
        for (int rr = 0; rr < 4; rr++) {
            float mnew  = fmaxf(mrow[rr], tmax[rr]);
            float scale = __expf(mrow[rr] - mnew);
            mrow[rr] = mnew;
            float s = 0.f;
#pragma unroll
            for (int nt = 0; nt < 4; nt++) {
                float pv = __expf(p[nt][rr] - mnew);
                p[nt][rr] = pv;
                s += pv;
            }
            ssum[rr] = s;
            lrow[rr] *= scale;
#pragma unroll
            for (int no = 0; no < 4; no++) oacc[no][rr] *= scale;
        }
#pragma unroll
        for (int rr = 0; rr < 4; rr++) {
#pragma unroll
            for (int m = 1; m < 16; m <<= 1) ssum[rr] += __shfl_xor(ssum[rr], m);
            lrow[rr] += ssum[rr];
        }
        // P -> bf16 via per-wave LDS transpose
#pragma unroll
        for (int nt = 0; nt < 4; nt++)
#pragma unroll
            for (int rr = 0; rr < 4; rr++)
                Pw[w][lg * 4 + rr][nt * 16 + l15] = f2bf(p[nt][rr]);

        // --- PV ---
        const u16* vt0 = vbh + t * 64;
#pragma unroll
        for (int cch = 0; cch < 2; cch++) {
            short8 pf = *reinterpret_cast<const short8*>(&Pw[w][l15][cch * 32 + 8 * lg]);
#pragma unroll
            for (int no = 0; no < 4; no++) {
                short8 vf = *reinterpret_cast<const short8*>(
                    vt0 + (size_t)(no * 16 + l15) * 2048 + cch * 32 + 8 * lg);
                oacc[no] = __builtin_amdgcn_mfma_f32_16x16x32_bf16(pf, vf, oacc[no], 0, 0, 0);
            }
        }
    }

#pragma unroll
    for (int no = 0; no < 4; no++)
#pragma unroll
        for (int rr = 0; rr < 4; rr++) {
            int n   = n0 + lg * 4 + rr;
            int col = h * 64 + no * 16 + l15;
            float val = oacc[no][rr] / lrow[rr];
            ob[((size_t)(b * 2048 + n)) * 1024 + col] = f2bf(val);
        }
}

// ---------------------------------------------------------------------------
extern "C" void kernel_launch(void* const* d_in, const int* in_sizes, int n_in,
                              void* d_out, int out_size, void* d_ws, size_t ws_size,
                              hipStream_t stream)
{
    const float* x        = (const float*)d_in[0];
    const float* Wq       = (const float*)d_in[1];
    const float* Wk       = (const float*)d_in[2];
    const float* Wv       = (const float*)d_in[3];
    const float* Wo       = (const float*)d_in[4];
    const float* log_c    = (const float*)d_in[5];
    const float* log_beta = (const float*)d_in[6];
    float* out = (float*)d_out;

    char* ws = (char*)d_ws;
    u16* xb  = (u16*)(ws);
    u16* wqb = (u16*)(ws + ((size_t)8  << 20));
    u16* wkb = (u16*)(ws + ((size_t)10 << 20));
    u16* wvb = (u16*)(ws + ((size_t)12 << 20));
    u16* wob = (u16*)(ws + ((size_t)14 << 20));
    u16* qb  = (u16*)(ws + ((size_t)16 << 20));
    u16* kb  = (u16*)(ws + ((size_t)24 << 20));
    u16* vb  = (u16*)(ws + ((size_t)32 << 20));   // dead after transpose; reused as ob
    u16* vt  = (u16*)(ws + ((size_t)40 << 20));
    float* qn = (float*)(ws + ((size_t)48 << 20));
    float* kn = (float*)(ws + ((size_t)48 << 20) + ((size_t)256 << 10));
    u16* ob = vb;

    castx_kernel<<<4096, 256, 0, stream>>>(x, Wq, Wk, Wv, Wo, xb, wqb, wkb, wvb, wob);
    gemm_qkv_kernel<<<dim3(8, 32, 3), 256, 0, stream>>>(xb, wqb, wkb, wvb, qb, kb, vb, qn, kn);
    transpose_v_kernel<<<1024, 256, 0, stream>>>(vb, vt);
    hypattn_kernel<<<2048, 128, 0, stream>>>(qb, kb, vt, qn, kn, ob, log_c, log_beta);
    gemm_out_kernel<<<dim3(8, 32), 256, 0, stream>>>(ob, wob, out);
}

// Round 3
// 229.829 us; speedup vs baseline: 1.8692x; 1.1070x over previous
//
#include <hip/hip_runtime.h>
#include <cstdint>
#include <cstddef>

using short8 = __attribute__((ext_vector_type(8))) short;
using f32x4  = __attribute__((ext_vector_type(4))) float;
typedef unsigned short u16;
typedef unsigned int   u32;

__device__ __forceinline__ u16 f2bf(float f) {
    uint32_t u = __builtin_bit_cast(uint32_t, f);
    u += 0x7fffu + ((u >> 16) & 1u);
    return (u16)(u >> 16);
}

__device__ __forceinline__ void gload_lds16(const u16* g, u16* l) {
    __builtin_amdgcn_global_load_lds(
        (const __attribute__((address_space(1))) u32*)g,
        (__attribute__((address_space(3))) u32*)l, 16, 0, 0);
}

// ---------------------------------------------------------------------------
// fp32 -> bf16 cast of x (4M elems) and Wq/Wk/Wv/Wo (1M each)
// ---------------------------------------------------------------------------
__global__ __launch_bounds__(256) void castx_kernel(
    const float* __restrict__ x,  const float* __restrict__ wq,
    const float* __restrict__ wk, const float* __restrict__ wv,
    const float* __restrict__ wo,
    u16* __restrict__ xb,  u16* __restrict__ wqb, u16* __restrict__ wkb,
    u16* __restrict__ wvb, u16* __restrict__ wob)
{
    size_t i = ((size_t)blockIdx.x * 256 + threadIdx.x) * 8;
    const float* src; u16* dst; size_t off;
    if (i < (size_t)(4u << 20)) { src = x; dst = xb; off = i; }
    else {
        size_t j = i - (size_t)(4u << 20);
        int sel = (int)(j >> 20);
        off = j & (((size_t)1 << 20) - 1);
        src = sel == 0 ? wq : sel == 1 ? wk : sel == 2 ? wv : wo;
        dst = sel == 0 ? wqb : sel == 1 ? wkb : sel == 2 ? wvb : wob;
    }
    float4 a = *reinterpret_cast<const float4*>(src + off);
    float4 b = *reinterpret_cast<const float4*>(src + off + 4);
    short8 o;
    o[0] = (short)f2bf(a.x); o[1] = (short)f2bf(a.y);
    o[2] = (short)f2bf(a.z); o[3] = (short)f2bf(a.w);
    o[4] = (short)f2bf(b.x); o[5] = (short)f2bf(b.y);
    o[6] = (short)f2bf(b.z); o[7] = (short)f2bf(b.w);
    *reinterpret_cast<short8*>(dst + off) = o;
}

// ---------------------------------------------------------------------------
// m97-style GEMM core: 128x128 tile, BK=64, global_load_lds width 16.
// C = A[M][K] * B[N][K]^T, A/B bf16. K=1024 (16 K-steps).
// ---------------------------------------------------------------------------
__device__ __forceinline__ void gemm_core(const u16* __restrict__ A,
                                          const u16* __restrict__ Bw,
                                          u16* As, u16* Bs,
                                          int rowA, int colB,
                                          f32x4 acc[4][4])
{
    const int tid = threadIdx.x, lane = tid & 63, w = tid >> 6;
    const int l15 = lane & 15, lg = lane >> 4;
    const int wr = w >> 1, wc = w & 1;
    const int srow = lane >> 3, scol = (lane & 7) * 8;
    constexpr int K = 1024;

    for (int kt = 0; kt < 16; ++kt) {
        __syncthreads();
#pragma unroll
        for (int i = 0; i < 4; i++) {
            int r = w * 32 + i * 8;
            gload_lds16(A  + (size_t)(rowA + r + srow) * K + kt * 64 + scol, As + r * 64);
            gload_lds16(Bw + (size_t)(colB + r + srow) * K + kt * 64 + scol, Bs + r * 64);
        }
        __syncthreads();
#pragma unroll
        for (int c = 0; c < 2; c++) {
            short8 af[4], bf[4];
#pragma unroll
            for (int mi = 0; mi < 4; mi++)
                af[mi] = *reinterpret_cast<const short8*>(As + (wr*64 + mi*16 + l15)*64 + c*32 + 8*lg);
#pragma unroll
            for (int ni = 0; ni < 4; ni++)
                bf[ni] = *reinterpret_cast<const short8*>(Bs + (wc*64 + ni*16 + l15)*64 + c*32 + 8*lg);
#pragma unroll
            for (int mi = 0; mi < 4; mi++)
#pragma unroll
                for (int ni = 0; ni < 4; ni++)
                    acc[mi][ni] = __builtin_amdgcn_mfma_f32_16x16x32_bf16(af[mi], bf[ni], acc[mi][ni], 0, 0, 0);
        }
    }
}

// QKV fused: grid (8, 32, 3). Writes bf16 q/k/v + fp32 row-norms for q,k.
__global__ __launch_bounds__(256) void gemm_qkv_kernel(
    const u16* __restrict__ xb,
    const u16* __restrict__ w0, const u16* __restrict__ w1, const u16* __restrict__ w2,
    u16* __restrict__ c0, u16* __restrict__ c1, u16* __restrict__ c2,
    float* __restrict__ qn, float* __restrict__ kn)
{
    __shared__ __align__(16) u16 As[128 * 64];
    __shared__ __align__(16) u16 Bs[128 * 64];
    const int z = blockIdx.z;
    const u16* W = z == 0 ? w0 : (z == 1 ? w1 : w2);
    u16* C       = z == 0 ? c0 : (z == 1 ? c1 : c2);
    float* nrm   = z == 0 ? qn : (z == 1 ? kn : nullptr);
    const int rowA = blockIdx.y * 128, colB = blockIdx.x * 128;

    f32x4 acc[4][4] = {};
    gemm_core(xb, W, As, Bs, rowA, colB, acc);

    const int tid = threadIdx.x, lane = tid & 63, w = tid >> 6;
    const int l15 = lane & 15, lg = lane >> 4;
    const int wr = w >> 1, wc = w & 1;
#pragma unroll
    for (int mi = 0; mi < 4; mi++)
#pragma unroll
        for (int ni = 0; ni < 4; ni++)
#pragma unroll
            for (int rr = 0; rr < 4; rr++) {
                int row = rowA + wr*64 + mi*16 + lg*4 + rr;
                int col = colB + wc*64 + ni*16 + l15;
                C[(size_t)row * 1024 + col] = f2bf(acc[mi][ni][rr]);
            }
    if (nrm) {
        int hh = blockIdx.x * 2 + wc;
#pragma unroll
        for (int mi = 0; mi < 4; mi++)
#pragma unroll
            for (int rr = 0; rr < 4; rr++) {
                float s = 0.f;
#pragma unroll
                for (int ni = 0; ni < 4; ni++) { float v = acc[mi][ni][rr]; s += v * v; }
#pragma unroll
                for (int m = 1; m < 16; m <<= 1) s += __shfl_xor(s, m);
                if (l15 == 0) {
                    int row = rowA + wr*64 + mi*16 + lg*4 + rr;
                    nrm[((size_t)(row >> 11) * 16 + hh) * 2048 + (row & 2047)] = s;
                }
            }
    }
}

// Final projection: fp32 out. grid (8, 32).
__global__ __launch_bounds__(256) void gemm_out_kernel(
    const u16* __restrict__ ob, const u16* __restrict__ wob, float* __restrict__ out)
{
    __shared__ __align__(16) u16 As[128 * 64];
    __shared__ __align__(16) u16 Bs[128 * 64];
    const int rowA = blockIdx.y * 128, colB = blockIdx.x * 128;
    f32x4 acc[4][4] = {};
    gemm_core(ob, wob, As, Bs, rowA, colB, acc);
    const int tid = threadIdx.x, lane = tid & 63, w = tid >> 6;
    const int l15 = lane & 15, lg = lane >> 4;
    const int wr = w >> 1, wc = w & 1;
#pragma unroll
    for (int mi = 0; mi < 4; mi++)
#pragma unroll
        for (int ni = 0; ni < 4; ni++)
#pragma unroll
            for (int rr = 0; rr < 4; rr++) {
                int row = rowA + wr*64 + mi*16 + lg*4 + rr;
                int col = colB + wc*64 + ni*16 + l15;
                out[(size_t)row * 1024 + col] = acc[mi][ni][rr];
            }
}

// ---------------------------------------------------------------------------
// V transpose: vb [B*N][D] -> vt [(b*16+h)*64+d][N]  (bf16)
// ---------------------------------------------------------------------------
__global__ __launch_bounds__(256) void transpose_v_kernel(const u16* __restrict__ vb,
                                                          u16* __restrict__ vt)
{
    __shared__ __align__(16) u16 T[64][80];
    const int bid = blockIdx.x;
    const int bh = bid >> 5, tile = bid & 31;
    const int b = bh >> 4, h = bh & 15;
#pragma unroll
    for (int i = 0; i < 2; i++) {
        int flat = threadIdx.x + i * 256;      // 0..511
        int r = flat >> 3, c8 = (flat & 7) * 8;
        short8 v = *reinterpret_cast<const short8*>(
            vb + (size_t)(b * 2048 + tile * 64 + r) * 1024 + h * 64 + c8);
#pragma unroll
        for (int e = 0; e < 8; e++) T[c8 + e][r] = (u16)v[e];
    }
    __syncthreads();
#pragma unroll
    for (int i = 0; i < 2; i++) {
        int flat = threadIdx.x + i * 256;
        int d = flat >> 3, c8 = (flat & 7) * 8;
        short8 v = *reinterpret_cast<const short8*>(&T[d][c8]);
        *reinterpret_cast<short8*>(vt + ((size_t)bh * 64 + d) * 2048 + tile * 64 + c8) = v;
    }
}

// ---------------------------------------------------------------------------
// Fused causal hyperbolic flash attention, fixed-shift softmax (all scores<=0).
// Block = 4 waves on ONE 16-row Q group; KV tiles split t = w mod 4.
// Partials combined in LDS by plain summation. grid 4096 x 256.
// ---------------------------------------------------------------------------
__global__ __launch_bounds__(256) void hypattn_kernel(
    const u16* __restrict__ qb, const u16* __restrict__ kb, const u16* __restrict__ vt,
    const float* __restrict__ qnp, const float* __restrict__ knp,
    u16* __restrict__ ob, const float* __restrict__ log_c, const float* __restrict__ log_beta)
{
    __shared__ __align__(16) u16   Pw[4][16][72];
    __shared__ __align__(16) float Po[4][16][68];
    __shared__ float Pl[4][16];

    const int tid  = threadIdx.x;
    const int w    = tid >> 6;
    const int lane = tid & 63;
    const int l15  = lane & 15;
    const int lg   = lane >> 4;

    // XCD-chunked swizzle + big-tiles-first
    const int swz = (blockIdx.x & 7) * 512 + (blockIdx.x >> 3);
    const int wt  = 4095 - swz;
    const int bh  = wt >> 7;
    const int j   = wt & 127;
    const int b   = bh >> 4, h = bh & 15;
    const int n0  = j * 16;
    const int ntiles = (j >> 2) + 1;

    const float cc   = log1pf(__expf(log_c[0]));
    const float beta = log1pf(__expf(log_beta[0])) + 0.5f;

    short8 qf[2];
    {
        size_t base = ((size_t)(b * 2048 + n0 + l15)) * 1024 + h * 64;
        qf[0] = *reinterpret_cast<const short8*>(qb + base);
        qf[1] = *reinterpret_cast<const short8*>(qb + base + 32 + 8 * lg - 8 * lg);
        qf[0] = *reinterpret_cast<const short8*>(qb + base + 8 * lg);
        qf[1] = *reinterpret_cast<const short8*>(qb + base + 32 + 8 * lg);
    }
    float qnr[4];
#pragma unroll
    for (int rr = 0; rr < 4; rr++)
        qnr[rr] = qnp[(size_t)bh * 2048 + n0 + lg * 4 + rr];

    float psum[4] = {0.f, 0.f, 0.f, 0.f};
    f32x4 oacc[4] = {};

    const u16* kbh = kb + (size_t)b * 2048 * 1024 + h * 64;
    const u16* vbh = vt + (size_t)bh * 64 * 2048;
    const float* knb = knp + (size_t)bh * 2048;

    for (int t = w; t < ntiles; t += 4) {
        // --- QK^T ---
        f32x4 sacc[4] = {};
        {
            const u16* kt0 = kbh + (size_t)(t * 64) * 1024;
#pragma unroll
            for (int cch = 0; cch < 2; cch++)
#pragma unroll
                for (int nt = 0; nt < 4; nt++) {
                    short8 kf = *reinterpret_cast<const short8*>(
                        kt0 + (size_t)(nt * 16 + l15) * 1024 + cch * 32 + 8 * lg);
                    sacc[nt] = __builtin_amdgcn_mfma_f32_16x16x32_bf16(qf[cch], kf, sacc[nt], 0, 0, 0);
                }
        }
        float knj[4];
#pragma unroll
        for (int nt = 0; nt < 4; nt++) knj[nt] = knb[t * 64 + nt * 16 + l15];

        // --- distance -> p = exp(score), fixed shift m=0 (scores <= 0) ---
        float p[4][4], d2s[4][4];
        float d2min = 1e30f;
#pragma unroll
        for (int nt = 0; nt < 4; nt++)
#pragma unroll
            for (int rr = 0; rr < 4; rr++) {
                float qk = sacc[nt][rr];
                float ns = qnr[rr] + knj[nt];
                float d2 = fmaxf(ns - 2.f * qk, 0.f);
                d2s[nt][rr] = d2;
                d2min = fminf(d2min, d2);
                float cn  = cc * ns;
                // ed>2 path: log(ed) = 0.5*log(d2)  (sqrt-free)
                float lgv = __builtin_amdgcn_logf(d2 + 1e-8f);
                float dist = 0.693f + 0.34657359f * lgv + 0.25f * cn;
                p[nt][rr] = __expf(-beta * dist);
            }
        if (__any(d2min <= 4.0f)) {           // exact fixup (diagonal tiles only)
#pragma unroll
            for (int nt = 0; nt < 4; nt++)
#pragma unroll
                for (int rr = 0; rr < 4; rr++) {
                    float d2v = d2s[nt][rr];
                    if (d2v <= 4.0f) {        // => ed <= 2: taylor or standard branch
                        float ed = sqrtf(d2v + 1e-8f);
                        float ns = qnr[rr] + knj[nt];
                        float cn = cc * ns;
                        float dist = (ed < 0.1f)
                            ? ed * (1.f + 0.5f * cn + 0.125f * cn * cn)
                            : ed * sqrtf(1.f + cn);
                        p[nt][rr] = __expf(-beta * dist);
                    }
                }
        }
        // --- causal mask (post-hoc), psum accumulate, P -> bf16 LDS ---
        const bool lastt = (t == ntiles - 1);
#pragma unroll
        for (int nt = 0; nt < 4; nt++)
#pragma unroll
            for (int rr = 0; rr < 4; rr++) {
                float pv = p[nt][rr];
                if (lastt && (t * 64 + nt * 16 + l15 > n0 + lg * 4 + rr)) pv = 0.f;
                psum[rr] += pv;
                Pw[w][lg * 4 + rr][nt * 16 + l15] = f2bf(pv);
            }
        // --- PV ---
        const u16* vt0 = vbh + t * 64;
#pragma unroll
        for (int cch = 0; cch < 2; cch++) {
            short8 pf = *reinterpret_cast<const short8*>(&Pw[w][l15][cch * 32 + 8 * lg]);
#pragma unroll
            for (int no = 0; no < 4; no++) {
                short8 vf = *reinterpret_cast<const short8*>(
                    vt0 + (size_t)(no * 16 + l15) * 2048 + cch * 32 + 8 * lg);
                oacc[no] = __builtin_amdgcn_mfma_f32_16x16x32_bf16(pf, vf, oacc[no], 0, 0, 0);
            }
        }
    }

    // --- write this wave's partial (O, l) to LDS ---
#pragma unroll
    for (int rr = 0; rr < 4; rr++) {
#pragma unroll
        for (int m = 1; m < 16; m <<= 1) psum[rr] += __shfl_xor(psum[rr], m);
    }
#pragma unroll
    for (int no = 0; no < 4; no++)
#pragma unroll
        for (int rr = 0; rr < 4; rr++)
            Po[w][lg * 4 + rr][no * 16 + l15] = oacc[no][rr];
    if (l15 == 0) {
#pragma unroll
        for (int rr = 0; rr < 4; rr++) Pl[w][lg * 4 + rr] = psum[rr];
    }
    __syncthreads();

    // --- combine 4 partials (plain sums), normalize, store bf16 ---
    {
        int r  = tid >> 4;          // 0..15
        int c4 = (tid & 15) * 4;    // 0..60
        float4 s = make_float4(0.f, 0.f, 0.f, 0.f);
        float l = 0.f;
#pragma unroll
        for (int w2 = 0; w2 < 4; w2++) {
            float4 t = *reinterpret_cast<const float4*>(&Po[w2][r][c4]);
            s.x += t.x; s.y += t.y; s.z += t.z; s.w += t.w;
            l += Pl[w2][r];
        }
        float inv = 1.f / l;
        ushort4 o;
        o.x = f2bf(s.x * inv); o.y = f2bf(s.y * inv);
        o.z = f2bf(s.z * inv); o.w = f2bf(s.w * inv);
        *reinterpret_cast<ushort4*>(
            ob + ((size_t)(b * 2048 + n0 + r)) * 1024 + h * 64 + c4) = o;
    }
}

// ---------------------------------------------------------------------------
extern "C" void kernel_launch(void* const* d_in, const int* in_sizes, int n_in,
                              void* d_out, int out_size, void* d_ws, size_t ws_size,
                              hipStream_t stream)
{
    const float* x        = (const float*)d_in[0];
    const float* Wq       = (const float*)d_in[1];
    const float* Wk       = (const float*)d_in[2];
    const float* Wv       = (const float*)d_in[3];
    const float* Wo       = (const float*)d_in[4];
    const float* log_c    = (const float*)d_in[5];
    const float* log_beta = (const float*)d_in[6];
    float* out = (float*)d_out;

    char* ws = (char*)d_ws;
    u16* xb  = (u16*)(ws);
    u16* wqb = (u16*)(ws + ((size_t)8  << 20));
    u16* wkb = (u16*)(ws + ((size_t)10 << 20));
    u16* wvb = (u16*)(ws + ((size_t)12 << 20));
    u16* wob = (u16*)(ws + ((size_t)14 << 20));
    u16* qb  = (u16*)(ws + ((size_t)16 << 20));
    u16* kb  = (u16*)(ws + ((size_t)24 << 20));
    u16* vb  = (u16*)(ws + ((size_t)32 << 20));   // dead after transpose; reused as ob
    u16* vt  = (u16*)(ws + ((size_t)40 << 20));
    float* qn = (float*)(ws + ((size_t)48 << 20));
    float* kn = (float*)(ws + ((size_t)48 << 20) + ((size_t)256 << 10));
    u16* ob = vb;

    castx_kernel<<<4096, 256, 0, stream>>>(x, Wq, Wk, Wv, Wo, xb, wqb, wkb, wvb, wob);
    gemm_qkv_kernel<<<dim3(8, 32, 3), 256, 0, stream>>>(xb, wqb, wkb, wvb, qb, kb, vb, qn, kn);
    transpose_v_kernel<<<1024, 256, 0, stream>>>(vb, vt);
    hypattn_kernel<<<4096, 256, 0, stream>>>(qb, kb, vt, qn, kn, ob, log_c, log_beta);
    gemm_out_kernel<<<dim3(8, 32), 256, 0, stream>>>(ob, wob, out);
}

// Round 4
// 215.211 us; speedup vs baseline: 1.9962x; 1.0679x over previous
//
#include <hip/hip_runtime.h>
#include <cstdint>
#include <cstddef>

using short8 = __attribute__((ext_vector_type(8))) short;
using f32x4  = __attribute__((ext_vector_type(4))) float;
typedef unsigned short u16;
typedef unsigned int   u32;

__device__ __forceinline__ u16 f2bf(float f) {
    uint32_t u = __builtin_bit_cast(uint32_t, f);
    u += 0x7fffu + ((u >> 16) & 1u);
    return (u16)(u >> 16);
}

__device__ __forceinline__ void gload_lds16(const u16* g, u16* l) {
    __builtin_amdgcn_global_load_lds(
        (const __attribute__((address_space(1))) u32*)g,
        (__attribute__((address_space(3))) u32*)l, 16, 0, 0);
}

// ---------------------------------------------------------------------------
// fp32 -> bf16 cast of x (4M elems) and Wq/Wk/Wv/Wo (1M each)
// ---------------------------------------------------------------------------
__global__ __launch_bounds__(256) void castx_kernel(
    const float* __restrict__ x,  const float* __restrict__ wq,
    const float* __restrict__ wk, const float* __restrict__ wv,
    const float* __restrict__ wo,
    u16* __restrict__ xb,  u16* __restrict__ wqb, u16* __restrict__ wkb,
    u16* __restrict__ wvb, u16* __restrict__ wob)
{
    size_t i = ((size_t)blockIdx.x * 256 + threadIdx.x) * 8;
    const float* src; u16* dst; size_t off;
    if (i < (size_t)(4u << 20)) { src = x; dst = xb; off = i; }
    else {
        size_t j = i - (size_t)(4u << 20);
        int sel = (int)(j >> 20);
        off = j & (((size_t)1 << 20) - 1);
        src = sel == 0 ? wq : sel == 1 ? wk : sel == 2 ? wv : wo;
        dst = sel == 0 ? wqb : sel == 1 ? wkb : sel == 2 ? wvb : wob;
    }
    float4 a = *reinterpret_cast<const float4*>(src + off);
    float4 b = *reinterpret_cast<const float4*>(src + off + 4);
    short8 o;
    o[0] = (short)f2bf(a.x); o[1] = (short)f2bf(a.y);
    o[2] = (short)f2bf(a.z); o[3] = (short)f2bf(a.w);
    o[4] = (short)f2bf(b.x); o[5] = (short)f2bf(b.y);
    o[6] = (short)f2bf(b.z); o[7] = (short)f2bf(b.w);
    *reinterpret_cast<short8*>(dst + off) = o;
}

// ---------------------------------------------------------------------------
// m97-style GEMM core: 128x128 tile, BK=64, global_load_lds width 16.
// C = A[M][K] * B[N][K]^T, A/B bf16. K=1024 (16 K-steps).
// ---------------------------------------------------------------------------
__device__ __forceinline__ void gemm_core(const u16* __restrict__ A,
                                          const u16* __restrict__ Bw,
                                          u16* As, u16* Bs,
                                          int rowA, int colB,
                                          f32x4 acc[4][4])
{
    const int tid = threadIdx.x, lane = tid & 63, w = tid >> 6;
    const int l15 = lane & 15, lg = lane >> 4;
    const int wr = w >> 1, wc = w & 1;
    const int srow = lane >> 3, scol = (lane & 7) * 8;
    constexpr int K = 1024;

    for (int kt = 0; kt < 16; ++kt) {
        __syncthreads();
#pragma unroll
        for (int i = 0; i < 4; i++) {
            int r = w * 32 + i * 8;
            gload_lds16(A  + (size_t)(rowA + r + srow) * K + kt * 64 + scol, As + r * 64);
            gload_lds16(Bw + (size_t)(colB + r + srow) * K + kt * 64 + scol, Bs + r * 64);
        }
        __syncthreads();
#pragma unroll
        for (int c = 0; c < 2; c++) {
            short8 af[4], bf[4];
#pragma unroll
            for (int mi = 0; mi < 4; mi++)
                af[mi] = *reinterpret_cast<const short8*>(As + (wr*64 + mi*16 + l15)*64 + c*32 + 8*lg);
#pragma unroll
            for (int ni = 0; ni < 4; ni++)
                bf[ni] = *reinterpret_cast<const short8*>(Bs + (wc*64 + ni*16 + l15)*64 + c*32 + 8*lg);
#pragma unroll
            for (int mi = 0; mi < 4; mi++)
#pragma unroll
                for (int ni = 0; ni < 4; ni++)
                    acc[mi][ni] = __builtin_amdgcn_mfma_f32_16x16x32_bf16(af[mi], bf[ni], acc[mi][ni], 0, 0, 0);
        }
    }
}

// QKV fused: grid (8, 32, 3). Writes bf16 q/k/v + fp32 row-norms for q,k.
__global__ __launch_bounds__(256) void gemm_qkv_kernel(
    const u16* __restrict__ xb,
    const u16* __restrict__ w0, const u16* __restrict__ w1, const u16* __restrict__ w2,
    u16* __restrict__ c0, u16* __restrict__ c1, u16* __restrict__ c2,
    float* __restrict__ qn, float* __restrict__ kn)
{
    __shared__ __align__(16) u16 As[128 * 64];
    __shared__ __align__(16) u16 Bs[128 * 64];
    const int z = blockIdx.z;
    const u16* W = z == 0 ? w0 : (z == 1 ? w1 : w2);
    u16* C       = z == 0 ? c0 : (z == 1 ? c1 : c2);
    float* nrm   = z == 0 ? qn : (z == 1 ? kn : nullptr);
    const int rowA = blockIdx.y * 128, colB = blockIdx.x * 128;

    f32x4 acc[4][4] = {};
    gemm_core(xb, W, As, Bs, rowA, colB, acc);

    const int tid = threadIdx.x, lane = tid & 63, w = tid >> 6;
    const int l15 = lane & 15, lg = lane >> 4;
    const int wr = w >> 1, wc = w & 1;
#pragma unroll
    for (int mi = 0; mi < 4; mi++)
#pragma unroll
        for (int ni = 0; ni < 4; ni++)
#pragma unroll
            for (int rr = 0; rr < 4; rr++) {
                int row = rowA + wr*64 + mi*16 + lg*4 + rr;
                int col = colB + wc*64 + ni*16 + l15;
                C[(size_t)row * 1024 + col] = f2bf(acc[mi][ni][rr]);
            }
    if (nrm) {
        int hh = blockIdx.x * 2 + wc;
#pragma unroll
        for (int mi = 0; mi < 4; mi++)
#pragma unroll
            for (int rr = 0; rr < 4; rr++) {
                float s = 0.f;
#pragma unroll
                for (int ni = 0; ni < 4; ni++) { float v = acc[mi][ni][rr]; s += v * v; }
#pragma unroll
                for (int m = 1; m < 16; m <<= 1) s += __shfl_xor(s, m);
                if (l15 == 0) {
                    int row = rowA + wr*64 + mi*16 + lg*4 + rr;
                    nrm[((size_t)(row >> 11) * 16 + hh) * 2048 + (row & 2047)] = s;
                }
            }
    }
}

// Final projection: fp32 out. grid (8, 32).
__global__ __launch_bounds__(256) void gemm_out_kernel(
    const u16* __restrict__ ob, const u16* __restrict__ wob, float* __restrict__ out)
{
    __shared__ __align__(16) u16 As[128 * 64];
    __shared__ __align__(16) u16 Bs[128 * 64];
    const int rowA = blockIdx.y * 128, colB = blockIdx.x * 128;
    f32x4 acc[4][4] = {};
    gemm_core(ob, wob, As, Bs, rowA, colB, acc);
    const int tid = threadIdx.x, lane = tid & 63, w = tid >> 6;
    const int l15 = lane & 15, lg = lane >> 4;
    const int wr = w >> 1, wc = w & 1;
#pragma unroll
    for (int mi = 0; mi < 4; mi++)
#pragma unroll
        for (int ni = 0; ni < 4; ni++)
#pragma unroll
            for (int rr = 0; rr < 4; rr++) {
                int row = rowA + wr*64 + mi*16 + lg*4 + rr;
                int col = colB + wc*64 + ni*16 + l15;
                out[(size_t)row * 1024 + col] = acc[mi][ni][rr];
            }
}

// ---------------------------------------------------------------------------
// V transpose: vb [B*N][D] -> vt [(b*16+h)*64+d][N]  (bf16)
// ---------------------------------------------------------------------------
__global__ __launch_bounds__(256) void transpose_v_kernel(const u16* __restrict__ vb,
                                                          u16* __restrict__ vt)
{
    __shared__ __align__(16) u16 T[64][80];
    const int bid = blockIdx.x;
    const int bh = bid >> 5, tile = bid & 31;
    const int b = bh >> 4, h = bh & 15;
#pragma unroll
    for (int i = 0; i < 2; i++) {
        int flat = threadIdx.x + i * 256;      // 0..511
        int r = flat >> 3, c8 = (flat & 7) * 8;
        short8 v = *reinterpret_cast<const short8*>(
            vb + (size_t)(b * 2048 + tile * 64 + r) * 1024 + h * 64 + c8);
#pragma unroll
        for (int e = 0; e < 8; e++) T[c8 + e][r] = (u16)v[e];
    }
    __syncthreads();
#pragma unroll
    for (int i = 0; i < 2; i++) {
        int flat = threadIdx.x + i * 256;
        int d = flat >> 3, c8 = (flat & 7) * 8;
        short8 v = *reinterpret_cast<const short8*>(&T[d][c8]);
        *reinterpret_cast<short8*>(vt + ((size_t)bh * 64 + d) * 2048 + tile * 64 + c8) = v;
    }
}

// ---------------------------------------------------------------------------
// Fused causal hyperbolic flash attention, fixed-shift softmax (scores <= 0).
// Block = 4 waves; each wave owns TWO 16-row Q groups (32 rows/block);
// KV tiles split t = w mod 4; K/V fragment loads amortized over both groups.
// grid 2048 x 256.
// ---------------------------------------------------------------------------
__global__ __launch_bounds__(256, 4) void hypattn_kernel(
    const u16* __restrict__ qb, const u16* __restrict__ kb, const u16* __restrict__ vt,
    const float* __restrict__ qnp, const float* __restrict__ knp,
    u16* __restrict__ ob, const float* __restrict__ log_c, const float* __restrict__ log_beta)
{
    // union: P staging [4][2][16][72] u16 (18432 B)  /  epilogue [4][16][68] f32 (17408 B)
    __shared__ __align__(16) char smem[4 * 2 * 16 * 72 * 2];
    __shared__ float Pl[4][2][16];
    u16 (*Pw)[2][16][72] = reinterpret_cast<u16 (*)[2][16][72]>(smem);
    float* SUf = reinterpret_cast<float*>(smem);

    const int tid  = threadIdx.x;
    const int w    = tid >> 6;
    const int lane = tid & 63;
    const int l15  = lane & 15;
    const int lg   = lane >> 4;

    // XCD-chunked swizzle (bijective: 2048 = 8*256) + big-tiles-first
    const int swz = (blockIdx.x & 7) * 256 + (blockIdx.x >> 3);
    const int wt  = 2047 - swz;
    const int bh  = wt >> 6;
    const int jj  = wt & 63;
    const int b   = bh >> 4, h = bh & 15;
    const int n0  = jj * 32;
    const int ntiles = (jj >> 1) + 1;

    const float cc   = log1pf(__expf(log_c[0]));
    const float beta = log1pf(__expf(log_beta[0])) + 0.5f;
    const float Aq = -beta * 0.693f * 1.44269504f;
    const float Bl = -beta * 0.5f;
    const float Cn = -beta * 0.25f * cc * 1.44269504f;

    short8 qf[2][2];
#pragma unroll
    for (int g = 0; g < 2; g++) {
        size_t base = ((size_t)(b * 2048 + n0 + g * 16 + l15)) * 1024 + h * 64;
        qf[g][0] = *reinterpret_cast<const short8*>(qb + base + 8 * lg);
        qf[g][1] = *reinterpret_cast<const short8*>(qb + base + 32 + 8 * lg);
    }
    float qnr[2][4];
#pragma unroll
    for (int g = 0; g < 2; g++)
#pragma unroll
        for (int rr = 0; rr < 4; rr++)
            qnr[g][rr] = qnp[(size_t)bh * 2048 + n0 + g * 16 + lg * 4 + rr];

    float psum[2][4] = {};
    f32x4 oacc0[4] = {}, oacc1[4] = {};

    const u16* kbh = kb + (size_t)b * 2048 * 1024 + h * 64;
    const u16* vbh = vt + (size_t)bh * 64 * 2048;
    const float* knb = knp + (size_t)bh * 2048;

#define PROC_GROUP(G, SACC)                                                     \
    {                                                                           \
      float p[4][4]; float d2min = 1e30f;                                       \
      _Pragma("unroll") for (int nt = 0; nt < 4; nt++)                          \
        _Pragma("unroll") for (int rr = 0; rr < 4; rr++) {                      \
          float qk = SACC[nt][rr];                                              \
          float ns = qnr[G][rr] + knj[nt];                                      \
          float d2 = __builtin_fmaf(qk, -2.f, ns);                              \
          d2min = fminf(d2min, d2);                                             \
          float lgv = __builtin_amdgcn_logf(d2);                                \
          p[nt][rr] = __builtin_amdgcn_exp2f(                                   \
              __builtin_fmaf(Bl, lgv, __builtin_fmaf(Cn, ns, Aq)));             \
        }                                                                       \
      if (__any(d2min <= 4.0f)) {                                               \
        _Pragma("unroll") for (int nt = 0; nt < 4; nt++)                        \
          _Pragma("unroll") for (int rr = 0; rr < 4; rr++) {                    \
            float qk = SACC[nt][rr];                                            \
            float ns = qnr[G][rr] + knj[nt];                                    \
            float d2v = fmaxf(__builtin_fmaf(qk, -2.f, ns), 0.f);               \
            if (d2v <= 4.0f) {                                                  \
              float ed = __builtin_amdgcn_sqrtf(d2v + 1e-8f);                   \
              float cn = cc * ns;                                               \
              float dist = (ed < 0.1f) ? ed * (1.f + 0.5f*cn + 0.125f*cn*cn)    \
                                       : ed * __builtin_amdgcn_sqrtf(1.f + cn); \
              p[nt][rr] = __expf(-beta * dist);                                 \
            }                                                                   \
          }                                                                     \
      }                                                                         \
      if (lastt) {                                                              \
        _Pragma("unroll") for (int nt = 0; nt < 4; nt++)                        \
          _Pragma("unroll") for (int rr = 0; rr < 4; rr++)                      \
            if (t*64 + nt*16 + l15 > n0 + (G)*16 + lg*4 + rr) p[nt][rr] = 0.f;  \
      }                                                                         \
      _Pragma("unroll") for (int nt = 0; nt < 4; nt++)                          \
        _Pragma("unroll") for (int rr = 0; rr < 4; rr++) {                      \
          psum[G][rr] += p[nt][rr];                                             \
          Pw[w][G][lg*4 + rr][nt*16 + l15] = f2bf(p[nt][rr]);                   \
        }                                                                       \
    }

    for (int t = w; t < ntiles; t += 4) {
        // --- QK^T for both groups, K fragments loaded once ---
        f32x4 sacc0[4] = {}, sacc1[4] = {};
        const u16* kt0 = kbh + (size_t)(t * 64) * 1024;
#pragma unroll
        for (int cch = 0; cch < 2; cch++)
#pragma unroll
            for (int nt = 0; nt < 4; nt++) {
                short8 kf = *reinterpret_cast<const short8*>(
                    kt0 + (size_t)(nt * 16 + l15) * 1024 + cch * 32 + 8 * lg);
                sacc0[nt] = __builtin_amdgcn_mfma_f32_16x16x32_bf16(qf[0][cch], kf, sacc0[nt], 0, 0, 0);
                sacc1[nt] = __builtin_amdgcn_mfma_f32_16x16x32_bf16(qf[1][cch], kf, sacc1[nt], 0, 0, 0);
            }
        float knj[4];
#pragma unroll
        for (int nt = 0; nt < 4; nt++) knj[nt] = knb[t * 64 + nt * 16 + l15];
        const bool lastt = (t == ntiles - 1);

        PROC_GROUP(0, sacc0)
        PROC_GROUP(1, sacc1)

        // --- PV for both groups, V fragments loaded once ---
        const u16* vt0 = vbh + t * 64;
#pragma unroll
        for (int cch = 0; cch < 2; cch++) {
            short8 pf0 = *reinterpret_cast<const short8*>(&Pw[w][0][l15][cch * 32 + 8 * lg]);
            short8 pf1 = *reinterpret_cast<const short8*>(&Pw[w][1][l15][cch * 32 + 8 * lg]);
#pragma unroll
            for (int no = 0; no < 4; no++) {
                short8 vf = *reinterpret_cast<const short8*>(
                    vt0 + (size_t)(no * 16 + l15) * 2048 + cch * 32 + 8 * lg);
                oacc0[no] = __builtin_amdgcn_mfma_f32_16x16x32_bf16(pf0, vf, oacc0[no], 0, 0, 0);
                oacc1[no] = __builtin_amdgcn_mfma_f32_16x16x32_bf16(pf1, vf, oacc1[no], 0, 0, 0);
            }
        }
    }
#undef PROC_GROUP

    // --- psum reduce within 16-lane groups, stash per-wave row sums ---
#pragma unroll
    for (int g = 0; g < 2; g++)
#pragma unroll
        for (int rr = 0; rr < 4; rr++) {
#pragma unroll
            for (int m = 1; m < 16; m <<= 1)
                psum[g][rr] += __shfl_xor(psum[g][rr], m);
        }
    if (l15 == 0) {
#pragma unroll
        for (int g = 0; g < 2; g++)
#pragma unroll
            for (int rr = 0; rr < 4; rr++)
                Pl[w][g][lg * 4 + rr] = psum[g][rr];
    }

#define EPILOG(G, OACC)                                                          \
    __syncthreads();                                                             \
    _Pragma("unroll") for (int no = 0; no < 4; no++)                             \
      _Pragma("unroll") for (int rr = 0; rr < 4; rr++)                           \
        SUf[(w * 16 + lg * 4 + rr) * 68 + no * 16 + l15] = OACC[no][rr];         \
    __syncthreads();                                                             \
    {                                                                            \
      int r = tid >> 4, c4 = (tid & 15) * 4;                                     \
      float4 s = make_float4(0.f, 0.f, 0.f, 0.f); float l = 0.f;                 \
      _Pragma("unroll") for (int w2 = 0; w2 < 4; w2++) {                         \
        const float4 tt = *reinterpret_cast<const float4*>(&SUf[(w2*16+r)*68+c4]);\
        s.x += tt.x; s.y += tt.y; s.z += tt.z; s.w += tt.w;                      \
        l += Pl[w2][G][r];                                                       \
      }                                                                          \
      float inv = 1.f / l;                                                       \
      ushort4 o; o.x = f2bf(s.x*inv); o.y = f2bf(s.y*inv);                       \
      o.z = f2bf(s.z*inv); o.w = f2bf(s.w*inv);                                  \
      *reinterpret_cast<ushort4*>(                                               \
          ob + ((size_t)(b*2048 + n0 + (G)*16 + r))*1024 + h*64 + c4) = o;       \
    }

    EPILOG(0, oacc0)
    __syncthreads();
    EPILOG(1, oacc1)
#undef EPILOG
}

// ---------------------------------------------------------------------------
extern "C" void kernel_launch(void* const* d_in, const int* in_sizes, int n_in,
                              void* d_out, int out_size, void* d_ws, size_t ws_size,
                              hipStream_t stream)
{
    const float* x        = (const float*)d_in[0];
    const float* Wq       = (const float*)d_in[1];
    const float* Wk       = (const float*)d_in[2];
    const float* Wv       = (const float*)d_in[3];
    const float* Wo       = (const float*)d_in[4];
    const float* log_c    = (const float*)d_in[5];
    const float* log_beta = (const float*)d_in[6];
    float* out = (float*)d_out;

    char* ws = (char*)d_ws;
    u16* xb  = (u16*)(ws);
    u16* wqb = (u16*)(ws + ((size_t)8  << 20));
    u16* wkb = (u16*)(ws + ((size_t)10 << 20));
    u16* wvb = (u16*)(ws + ((size_t)12 << 20));
    u16* wob = (u16*)(ws + ((size_t)14 << 20));
    u16* qb  = (u16*)(ws + ((size_t)16 << 20));
    u16* kb  = (u16*)(ws + ((size_t)24 << 20));
    u16* vb  = (u16*)(ws + ((size_t)32 << 20));   // dead after transpose; reused as ob
    u16* vt  = (u16*)(ws + ((size_t)40 << 20));
    float* qn = (float*)(ws + ((size_t)48 << 20));
    float* kn = (float*)(ws + ((size_t)48 << 20) + ((size_t)256 << 10));
    u16* ob = vb;

    castx_kernel<<<4096, 256, 0, stream>>>(x, Wq, Wk, Wv, Wo, xb, wqb, wkb, wvb, wob);
    gemm_qkv_kernel<<<dim3(8, 32, 3), 256, 0, stream>>>(xb, wqb, wkb, wvb, qb, kb, vb, qn, kn);
    transpose_v_kernel<<<1024, 256, 0, stream>>>(vb, vt);
    hypattn_kernel<<<2048, 256, 0, stream>>>(qb, kb, vt, qn, kn, ob, log_c, log_beta);
    gemm_out_kernel<<<dim3(8, 32), 256, 0, stream>>>(ob, wob, out);
}

// Round 5
// 181.392 us; speedup vs baseline: 2.3683x; 1.1864x over previous
//
#include <hip/hip_runtime.h>
#include <cstdint>
#include <cstddef>

using short8 = __attribute__((ext_vector_type(8))) short;
using f32x4  = __attribute__((ext_vector_type(4))) float;
typedef unsigned short u16;
typedef unsigned int   u32;

__device__ __forceinline__ u16 f2bf(float f) {
    uint32_t u = __builtin_bit_cast(uint32_t, f);
    u += 0x7fffu + ((u >> 16) & 1u);
    return (u16)(u >> 16);
}

__device__ __forceinline__ void gload_lds16(const u16* g, u16* l) {
    __builtin_amdgcn_global_load_lds(
        (const __attribute__((address_space(1))) u32*)g,
        (__attribute__((address_space(3))) u32*)l, 16, 0, 0);
}

// ---------------------------------------------------------------------------
// fp32 -> bf16 cast of x (4M elems) and Wq/Wk/Wv/Wo (1M each)
// ---------------------------------------------------------------------------
__global__ __launch_bounds__(256) void castx_kernel(
    const float* __restrict__ x,  const float* __restrict__ wq,
    const float* __restrict__ wk, const float* __restrict__ wv,
    const float* __restrict__ wo,
    u16* __restrict__ xb,  u16* __restrict__ wqb, u16* __restrict__ wkb,
    u16* __restrict__ wvb, u16* __restrict__ wob)
{
    size_t i = ((size_t)blockIdx.x * 256 + threadIdx.x) * 8;
    const float* src; u16* dst; size_t off;
    if (i < (size_t)(4u << 20)) { src = x; dst = xb; off = i; }
    else {
        size_t j = i - (size_t)(4u << 20);
        int sel = (int)(j >> 20);
        off = j & (((size_t)1 << 20) - 1);
        src = sel == 0 ? wq : sel == 1 ? wk : sel == 2 ? wv : wo;
        dst = sel == 0 ? wqb : sel == 1 ? wkb : sel == 2 ? wvb : wob;
    }
    float4 a = *reinterpret_cast<const float4*>(src + off);
    float4 b = *reinterpret_cast<const float4*>(src + off + 4);
    short8 o;
    o[0] = (short)f2bf(a.x); o[1] = (short)f2bf(a.y);
    o[2] = (short)f2bf(a.z); o[3] = (short)f2bf(a.w);
    o[4] = (short)f2bf(b.x); o[5] = (short)f2bf(b.y);
    o[6] = (short)f2bf(b.z); o[7] = (short)f2bf(b.w);
    *reinterpret_cast<short8*>(dst + off) = o;
}

// ---------------------------------------------------------------------------
// m97-style GEMM core: 128x128 tile, BK=64, global_load_lds width 16.
// C = A[M][K] * B[N][K]^T, A/B bf16. K=1024 (16 K-steps).
// ---------------------------------------------------------------------------
__device__ __forceinline__ void gemm_core(const u16* __restrict__ A,
                                          const u16* __restrict__ Bw,
                                          u16* As, u16* Bs,
                                          int rowA, int colB,
                                          f32x4 acc[4][4])
{
    const int tid = threadIdx.x, lane = tid & 63, w = tid >> 6;
    const int l15 = lane & 15, lg = lane >> 4;
    const int wr = w >> 1, wc = w & 1;
    const int srow = lane >> 3, scol = (lane & 7) * 8;
    constexpr int K = 1024;

    for (int kt = 0; kt < 16; ++kt) {
        __syncthreads();
#pragma unroll
        for (int i = 0; i < 4; i++) {
            int r = w * 32 + i * 8;
            gload_lds16(A  + (size_t)(rowA + r + srow) * K + kt * 64 + scol, As + r * 64);
            gload_lds16(Bw + (size_t)(colB + r + srow) * K + kt * 64 + scol, Bs + r * 64);
        }
        __syncthreads();
#pragma unroll
        for (int c = 0; c < 2; c++) {
            short8 af[4], bf[4];
#pragma unroll
            for (int mi = 0; mi < 4; mi++)
                af[mi] = *reinterpret_cast<const short8*>(As + (wr*64 + mi*16 + l15)*64 + c*32 + 8*lg);
#pragma unroll
            for (int ni = 0; ni < 4; ni++)
                bf[ni] = *reinterpret_cast<const short8*>(Bs + (wc*64 + ni*16 + l15)*64 + c*32 + 8*lg);
#pragma unroll
            for (int mi = 0; mi < 4; mi++)
#pragma unroll
                for (int ni = 0; ni < 4; ni++)
                    acc[mi][ni] = __builtin_amdgcn_mfma_f32_16x16x32_bf16(af[mi], bf[ni], acc[mi][ni], 0, 0, 0);
        }
    }
}

// QKV fused: grid (8, 32, 3). Writes bf16 q/k/v + fp32 row-norms for q,k.
__global__ __launch_bounds__(256) void gemm_qkv_kernel(
    const u16* __restrict__ xb,
    const u16* __restrict__ w0, const u16* __restrict__ w1, const u16* __restrict__ w2,
    u16* __restrict__ c0, u16* __restrict__ c1, u16* __restrict__ c2,
    float* __restrict__ qn, float* __restrict__ kn)
{
    __shared__ __align__(16) u16 As[128 * 64];
    __shared__ __align__(16) u16 Bs[128 * 64];
    const int z = blockIdx.z;
    const u16* W = z == 0 ? w0 : (z == 1 ? w1 : w2);
    u16* C       = z == 0 ? c0 : (z == 1 ? c1 : c2);
    float* nrm   = z == 0 ? qn : (z == 1 ? kn : nullptr);
    const int rowA = blockIdx.y * 128, colB = blockIdx.x * 128;

    f32x4 acc[4][4] = {};
    gemm_core(xb, W, As, Bs, rowA, colB, acc);

    const int tid = threadIdx.x, lane = tid & 63, w = tid >> 6;
    const int l15 = lane & 15, lg = lane >> 4;
    const int wr = w >> 1, wc = w & 1;
#pragma unroll
    for (int mi = 0; mi < 4; mi++)
#pragma unroll
        for (int ni = 0; ni < 4; ni++)
#pragma unroll
            for (int rr = 0; rr < 4; rr++) {
                int row = rowA + wr*64 + mi*16 + lg*4 + rr;
                int col = colB + wc*64 + ni*16 + l15;
                C[(size_t)row * 1024 + col] = f2bf(acc[mi][ni][rr]);
            }
    if (nrm) {
        int hh = blockIdx.x * 2 + wc;
#pragma unroll
        for (int mi = 0; mi < 4; mi++)
#pragma unroll
            for (int rr = 0; rr < 4; rr++) {
                float s = 0.f;
#pragma unroll
                for (int ni = 0; ni < 4; ni++) { float v = acc[mi][ni][rr]; s += v * v; }
#pragma unroll
                for (int m = 1; m < 16; m <<= 1) s += __shfl_xor(s, m);
                if (l15 == 0) {
                    int row = rowA + wr*64 + mi*16 + lg*4 + rr;
                    nrm[((size_t)(row >> 11) * 16 + hh) * 2048 + (row & 2047)] = s;
                }
            }
    }
}

// Final projection: fp32 out. grid (8, 32).
__global__ __launch_bounds__(256) void gemm_out_kernel(
    const u16* __restrict__ ob, const u16* __restrict__ wob, float* __restrict__ out)
{
    __shared__ __align__(16) u16 As[128 * 64];
    __shared__ __align__(16) u16 Bs[128 * 64];
    const int rowA = blockIdx.y * 128, colB = blockIdx.x * 128;
    f32x4 acc[4][4] = {};
    gemm_core(ob, wob, As, Bs, rowA, colB, acc);
    const int tid = threadIdx.x, lane = tid & 63, w = tid >> 6;
    const int l15 = lane & 15, lg = lane >> 4;
    const int wr = w >> 1, wc = w & 1;
#pragma unroll
    for (int mi = 0; mi < 4; mi++)
#pragma unroll
        for (int ni = 0; ni < 4; ni++)
#pragma unroll
            for (int rr = 0; rr < 4; rr++) {
                int row = rowA + wr*64 + mi*16 + lg*4 + rr;
                int col = colB + wc*64 + ni*16 + l15;
                out[(size_t)row * 1024 + col] = acc[mi][ni][rr];
            }
}

// ---------------------------------------------------------------------------
// V transpose: vb [B*N][D] -> vt [(b*16+h)*64+d][N]  (bf16)
// ---------------------------------------------------------------------------
__global__ __launch_bounds__(256) void transpose_v_kernel(const u16* __restrict__ vb,
                                                          u16* __restrict__ vt)
{
    __shared__ __align__(16) u16 T[64][80];
    const int bid = blockIdx.x;
    const int bh = bid >> 5, tile = bid & 31;
    const int b = bh >> 4, h = bh & 15;
#pragma unroll
    for (int i = 0; i < 2; i++) {
        int flat = threadIdx.x + i * 256;      // 0..511
        int r = flat >> 3, c8 = (flat & 7) * 8;
        short8 v = *reinterpret_cast<const short8*>(
            vb + (size_t)(b * 2048 + tile * 64 + r) * 1024 + h * 64 + c8);
#pragma unroll
        for (int e = 0; e < 8; e++) T[c8 + e][r] = (u16)v[e];
    }
    __syncthreads();
#pragma unroll
    for (int i = 0; i < 2; i++) {
        int flat = threadIdx.x + i * 256;
        int d = flat >> 3, c8 = (flat & 7) * 8;
        short8 v = *reinterpret_cast<const short8*>(&T[d][c8]);
        *reinterpret_cast<short8*>(vt + ((size_t)bh * 64 + d) * 2048 + tile * 64 + c8) = v;
    }
}

// ---------------------------------------------------------------------------
// Fused causal hyperbolic flash attention, fixed-shift softmax (scores <= 0).
// Block = 4 waves; each wave owns TWO 16-row Q groups (32 rows/block);
// KV tiles split t = w mod 4; K/V fragment loads amortized over both groups.
// grid 2048 x 256. NO min-wave launch bound (R4's (256,4) caused VGPR=64 +
// 130MB scratch spill traffic).
// ---------------------------------------------------------------------------
__global__ __launch_bounds__(256) void hypattn_kernel(
    const u16* __restrict__ qb, const u16* __restrict__ kb, const u16* __restrict__ vt,
    const float* __restrict__ qnp, const float* __restrict__ knp,
    u16* __restrict__ ob, const float* __restrict__ log_c, const float* __restrict__ log_beta)
{
    // union: P staging [4][2][16][72] u16 (18432 B)  /  epilogue [4][16][68] f32 (17408 B)
    __shared__ __align__(16) char smem[4 * 2 * 16 * 72 * 2];
    __shared__ float Pl[4][2][16];
    u16 (*Pw)[2][16][72] = reinterpret_cast<u16 (*)[2][16][72]>(smem);
    float* SUf = reinterpret_cast<float*>(smem);

    const int tid  = threadIdx.x;
    const int w    = tid >> 6;
    const int lane = tid & 63;
    const int l15  = lane & 15;
    const int lg   = lane >> 4;

    // XCD-chunked swizzle (bijective: 2048 = 8*256) + big-tiles-first
    const int swz = (blockIdx.x & 7) * 256 + (blockIdx.x >> 3);
    const int wt  = 2047 - swz;
    const int bh  = wt >> 6;
    const int jj  = wt & 63;
    const int b   = bh >> 4, h = bh & 15;
    const int n0  = jj * 32;
    const int ntiles = (jj >> 1) + 1;

    const float cc   = log1pf(__expf(log_c[0]));
    const float beta = log1pf(__expf(log_beta[0])) + 0.5f;
    const float Aq = -beta * 0.693f * 1.44269504f;
    const float Bl = -beta * 0.5f;
    const float Cn = -beta * 0.25f * cc * 1.44269504f;

    short8 qf[2][2];
#pragma unroll
    for (int g = 0; g < 2; g++) {
        size_t base = ((size_t)(b * 2048 + n0 + g * 16 + l15)) * 1024 + h * 64;
        qf[g][0] = *reinterpret_cast<const short8*>(qb + base + 8 * lg);
        qf[g][1] = *reinterpret_cast<const short8*>(qb + base + 32 + 8 * lg);
    }
    float qnr[2][4];
#pragma unroll
    for (int g = 0; g < 2; g++)
#pragma unroll
        for (int rr = 0; rr < 4; rr++)
            qnr[g][rr] = qnp[(size_t)bh * 2048 + n0 + g * 16 + lg * 4 + rr];

    float psum[2][4] = {};
    f32x4 oacc0[4] = {}, oacc1[4] = {};

    const u16* kbh = kb + (size_t)b * 2048 * 1024 + h * 64;
    const u16* vbh = vt + (size_t)bh * 64 * 2048;
    const float* knb = knp + (size_t)bh * 2048;

#define PROC_GROUP(G, SACC)                                                     \
    {                                                                           \
      float p[4][4]; float d2min = 1e30f;                                       \
      _Pragma("unroll") for (int nt = 0; nt < 4; nt++)                          \
        _Pragma("unroll") for (int rr = 0; rr < 4; rr++) {                      \
          float qk = SACC[nt][rr];                                              \
          float ns = qnr[G][rr] + knj[nt];                                      \
          float d2 = __builtin_fmaf(qk, -2.f, ns);                              \
          d2min = fminf(d2min, d2);                                             \
          float lgv = __builtin_amdgcn_logf(d2);                                \
          p[nt][rr] = __builtin_amdgcn_exp2f(                                   \
              __builtin_fmaf(Bl, lgv, __builtin_fmaf(Cn, ns, Aq)));             \
        }                                                                       \
      if (__any(d2min <= 4.0f)) {                                               \
        _Pragma("unroll") for (int nt = 0; nt < 4; nt++)                        \
          _Pragma("unroll") for (int rr = 0; rr < 4; rr++) {                    \
            float qk = SACC[nt][rr];                                            \
            float ns = qnr[G][rr] + knj[nt];                                    \
            float d2v = fmaxf(__builtin_fmaf(qk, -2.f, ns), 0.f);               \
            if (d2v <= 4.0f) {                                                  \
              float ed = __builtin_amdgcn_sqrtf(d2v + 1e-8f);                   \
              float cn = cc * ns;                                               \
              float dist = (ed < 0.1f) ? ed * (1.f + 0.5f*cn + 0.125f*cn*cn)    \
                                       : ed * __builtin_amdgcn_sqrtf(1.f + cn); \
              p[nt][rr] = __expf(-beta * dist);                                 \
            }                                                                   \
          }                                                                     \
      }                                                                         \
      if (lastt) {                                                              \
        _Pragma("unroll") for (int nt = 0; nt < 4; nt++)                        \
          _Pragma("unroll") for (int rr = 0; rr < 4; rr++)                      \
            if (t*64 + nt*16 + l15 > n0 + (G)*16 + lg*4 + rr) p[nt][rr] = 0.f;  \
      }                                                                         \
      _Pragma("unroll") for (int nt = 0; nt < 4; nt++)                          \
        _Pragma("unroll") for (int rr = 0; rr < 4; rr++) {                      \
          psum[G][rr] += p[nt][rr];                                             \
          Pw[w][G][lg*4 + rr][nt*16 + l15] = f2bf(p[nt][rr]);                   \
        }                                                                       \
    }

    for (int t = w; t < ntiles; t += 4) {
        // --- QK^T for both groups, K fragments loaded once ---
        f32x4 sacc0[4] = {}, sacc1[4] = {};
        const u16* kt0 = kbh + (size_t)(t * 64) * 1024;
        __builtin_amdgcn_s_setprio(1);
#pragma unroll
        for (int cch = 0; cch < 2; cch++)
#pragma unroll
            for (int nt = 0; nt < 4; nt++) {
                short8 kf = *reinterpret_cast<const short8*>(
                    kt0 + (size_t)(nt * 16 + l15) * 1024 + cch * 32 + 8 * lg);
                sacc0[nt] = __builtin_amdgcn_mfma_f32_16x16x32_bf16(qf[0][cch], kf, sacc0[nt], 0, 0, 0);
                sacc1[nt] = __builtin_amdgcn_mfma_f32_16x16x32_bf16(qf[1][cch], kf, sacc1[nt], 0, 0, 0);
            }
        __builtin_amdgcn_s_setprio(0);
        float knj[4];
#pragma unroll
        for (int nt = 0; nt < 4; nt++) knj[nt] = knb[t * 64 + nt * 16 + l15];
        const bool lastt = (t == ntiles - 1);

        PROC_GROUP(0, sacc0)
        PROC_GROUP(1, sacc1)

        // --- PV for both groups, V fragments loaded once ---
        const u16* vt0 = vbh + t * 64;
        __builtin_amdgcn_s_setprio(1);
#pragma unroll
        for (int cch = 0; cch < 2; cch++) {
            short8 pf0 = *reinterpret_cast<const short8*>(&Pw[w][0][l15][cch * 32 + 8 * lg]);
            short8 pf1 = *reinterpret_cast<const short8*>(&Pw[w][1][l15][cch * 32 + 8 * lg]);
#pragma unroll
            for (int no = 0; no < 4; no++) {
                short8 vf = *reinterpret_cast<const short8*>(
                    vt0 + (size_t)(no * 16 + l15) * 2048 + cch * 32 + 8 * lg);
                oacc0[no] = __builtin_amdgcn_mfma_f32_16x16x32_bf16(pf0, vf, oacc0[no], 0, 0, 0);
                oacc1[no] = __builtin_amdgcn_mfma_f32_16x16x32_bf16(pf1, vf, oacc1[no], 0, 0, 0);
            }
        }
        __builtin_amdgcn_s_setprio(0);
    }
#undef PROC_GROUP

    // --- psum reduce within 16-lane groups, stash per-wave row sums ---
#pragma unroll
    for (int g = 0; g < 2; g++)
#pragma unroll
        for (int rr = 0; rr < 4; rr++) {
#pragma unroll
            for (int m = 1; m < 16; m <<= 1)
                psum[g][rr] += __shfl_xor(psum[g][rr], m);
        }
    if (l15 == 0) {
#pragma unroll
        for (int g = 0; g < 2; g++)
#pragma unroll
            for (int rr = 0; rr < 4; rr++)
                Pl[w][g][lg * 4 + rr] = psum[g][rr];
    }

#define EPILOG(G, OACC)                                                          \
    __syncthreads();                                                             \
    _Pragma("unroll") for (int no = 0; no < 4; no++)                             \
      _Pragma("unroll") for (int rr = 0; rr < 4; rr++)                           \
        SUf[(w * 16 + lg * 4 + rr) * 68 + no * 16 + l15] = OACC[no][rr];         \
    __syncthreads();                                                             \
    {                                                                            \
      int r = tid >> 4, c4 = (tid & 15) * 4;                                     \
      float4 s = make_float4(0.f, 0.f, 0.f, 0.f); float l = 0.f;                 \
      _Pragma("unroll") for (int w2 = 0; w2 < 4; w2++) {                         \
        const float4 tt = *reinterpret_cast<const float4*>(&SUf[(w2*16+r)*68+c4]);\
        s.x += tt.x; s.y += tt.y; s.z += tt.z; s.w += tt.w;                      \
        l += Pl[w2][G][r];                                                       \
      }                                                                          \
      float inv = 1.f / l;                                                       \
      ushort4 o; o.x = f2bf(s.x*inv); o.y = f2bf(s.y*inv);                       \
      o.z = f2bf(s.z*inv); o.w = f2bf(s.w*inv);                                  \
      *reinterpret_cast<ushort4*>(                                               \
          ob + ((size_t)(b*2048 + n0 + (G)*16 + r))*1024 + h*64 + c4) = o;       \
    }

    EPILOG(0, oacc0)
    __syncthreads();
    EPILOG(1, oacc1)
#undef EPILOG
}

// ---------------------------------------------------------------------------
extern "C" void kernel_launch(void* const* d_in, const int* in_sizes, int n_in,
                              void* d_out, int out_size, void* d_ws, size_t ws_size,
                              hipStream_t stream)
{
    const float* x        = (const float*)d_in[0];
    const float* Wq       = (const float*)d_in[1];
    const float* Wk       = (const float*)d_in[2];
    const float* Wv       = (const float*)d_in[3];
    const float* Wo       = (const float*)d_in[4];
    const float* log_c    = (const float*)d_in[5];
    const float* log_beta = (const float*)d_in[6];
    float* out = (float*)d_out;

    char* ws = (char*)d_ws;
    u16* xb  = (u16*)(ws);
    u16* wqb = (u16*)(ws + ((size_t)8  << 20));
    u16* wkb = (u16*)(ws + ((size_t)10 << 20));
    u16* wvb = (u16*)(ws + ((size_t)12 << 20));
    u16* wob = (u16*)(ws + ((size_t)14 << 20));
    u16* qb  = (u16*)(ws + ((size_t)16 << 20));
    u16* kb  = (u16*)(ws + ((size_t)24 << 20));
    u16* vb  = (u16*)(ws + ((size_t)32 << 20));   // dead after transpose; reused as ob
    u16* vt  = (u16*)(ws + ((size_t)40 << 20));
    float* qn = (float*)(ws + ((size_t)48 << 20));
    float* kn = (float*)(ws + ((size_t)48 << 20) + ((size_t)256 << 10));
    u16* ob = vb;

    castx_kernel<<<4096, 256, 0, stream>>>(x, Wq, Wk, Wv, Wo, xb, wqb, wkb, wvb, wob);
    gemm_qkv_kernel<<<dim3(8, 32, 3), 256, 0, stream>>>(xb, wqb, wkb, wvb, qb, kb, vb, qn, kn);
    transpose_v_kernel<<<1024, 256, 0, stream>>>(vb, vt);
    hypattn_kernel<<<2048, 256, 0, stream>>>(qb, kb, vt, qn, kn, ob, log_c, log_beta);
    gemm_out_kernel<<<dim3(8, 32), 256, 0, stream>>>(ob, wob, out);
}

// Round 6
// 170.526 us; speedup vs baseline: 2.5192x; 1.0637x over previous
//
#include <hip/hip_runtime.h>
#include <cstdint>
#include <cstddef>

using short8 = __attribute__((ext_vector_type(8))) short;
using f32x4  = __attribute__((ext_vector_type(4))) float;
typedef unsigned short u16;
typedef unsigned int   u32;

__device__ __forceinline__ u16 f2bf(float f) {
    uint32_t u = __builtin_bit_cast(uint32_t, f);
    u += 0x7fffu + ((u >> 16) & 1u);
    return (u16)(u >> 16);
}

__device__ __forceinline__ void gload_lds16(const u16* g, u16* l) {
    __builtin_amdgcn_global_load_lds(
        (const __attribute__((address_space(1))) u32*)g,
        (__attribute__((address_space(3))) u32*)l, 16, 0, 0);
}

// ---------------------------------------------------------------------------
// fp32 -> bf16 cast of x (4M elems) and Wq/Wk/Wv/Wo (1M each)
// ---------------------------------------------------------------------------
__global__ __launch_bounds__(256) void castx_kernel(
    const float* __restrict__ x,  const float* __restrict__ wq,
    const float* __restrict__ wk, const float* __restrict__ wv,
    const float* __restrict__ wo,
    u16* __restrict__ xb,  u16* __restrict__ wqb, u16* __restrict__ wkb,
    u16* __restrict__ wvb, u16* __restrict__ wob)
{
    size_t i = ((size_t)blockIdx.x * 256 + threadIdx.x) * 8;
    const float* src; u16* dst; size_t off;
    if (i < (size_t)(4u << 20)) { src = x; dst = xb; off = i; }
    else {
        size_t j = i - (size_t)(4u << 20);
        int sel = (int)(j >> 20);
        off = j & (((size_t)1 << 20) - 1);
        src = sel == 0 ? wq : sel == 1 ? wk : sel == 2 ? wv : wo;
        dst = sel == 0 ? wqb : sel == 1 ? wkb : sel == 2 ? wvb : wob;
    }
    float4 a = *reinterpret_cast<const float4*>(src + off);
    float4 b = *reinterpret_cast<const float4*>(src + off + 4);
    short8 o;
    o[0] = (short)f2bf(a.x); o[1] = (short)f2bf(a.y);
    o[2] = (short)f2bf(a.z); o[3] = (short)f2bf(a.w);
    o[4] = (short)f2bf(b.x); o[5] = (short)f2bf(b.y);
    o[6] = (short)f2bf(b.z); o[7] = (short)f2bf(b.w);
    *reinterpret_cast<short8*>(dst + off) = o;
}

// ---------------------------------------------------------------------------
// m97-style GEMM core: 128x128 tile, BK=64, global_load_lds width 16.
// ---------------------------------------------------------------------------
__device__ __forceinline__ void gemm_core(const u16* __restrict__ A,
                                          const u16* __restrict__ Bw,
                                          u16* As, u16* Bs,
                                          int rowA, int colB,
                                          f32x4 acc[4][4])
{
    const int tid = threadIdx.x, lane = tid & 63, w = tid >> 6;
    const int l15 = lane & 15, lg = lane >> 4;
    const int wr = w >> 1, wc = w & 1;
    const int srow = lane >> 3, scol = (lane & 7) * 8;
    constexpr int K = 1024;

    for (int kt = 0; kt < 16; ++kt) {
        __syncthreads();
#pragma unroll
        for (int i = 0; i < 4; i++) {
            int r = w * 32 + i * 8;
            gload_lds16(A  + (size_t)(rowA + r + srow) * K + kt * 64 + scol, As + r * 64);
            gload_lds16(Bw + (size_t)(colB + r + srow) * K + kt * 64 + scol, Bs + r * 64);
        }
        __syncthreads();
#pragma unroll
        for (int c = 0; c < 2; c++) {
            short8 af[4], bf[4];
#pragma unroll
            for (int mi = 0; mi < 4; mi++)
                af[mi] = *reinterpret_cast<const short8*>(As + (wr*64 + mi*16 + l15)*64 + c*32 + 8*lg);
#pragma unroll
            for (int ni = 0; ni < 4; ni++)
                bf[ni] = *reinterpret_cast<const short8*>(Bs + (wc*64 + ni*16 + l15)*64 + c*32 + 8*lg);
#pragma unroll
            for (int mi = 0; mi < 4; mi++)
#pragma unroll
                for (int ni = 0; ni < 4; ni++)
                    acc[mi][ni] = __builtin_amdgcn_mfma_f32_16x16x32_bf16(af[mi], bf[ni], acc[mi][ni], 0, 0, 0);
        }
    }
}

// QKV fused: grid (8, 32, 3). Writes bf16 q/k/v + fp32 row-norms for q,k.
__global__ __launch_bounds__(256) void gemm_qkv_kernel(
    const u16* __restrict__ xb,
    const u16* __restrict__ w0, const u16* __restrict__ w1, const u16* __restrict__ w2,
    u16* __restrict__ c0, u16* __restrict__ c1, u16* __restrict__ c2,
    float* __restrict__ qn, float* __restrict__ kn)
{
    __shared__ __align__(16) u16 As[128 * 64];
    __shared__ __align__(16) u16 Bs[128 * 64];
    const int z = blockIdx.z;
    const u16* W = z == 0 ? w0 : (z == 1 ? w1 : w2);
    u16* C       = z == 0 ? c0 : (z == 1 ? c1 : c2);
    float* nrm   = z == 0 ? qn : (z == 1 ? kn : nullptr);
    const int rowA = blockIdx.y * 128, colB = blockIdx.x * 128;

    f32x4 acc[4][4] = {};
    gemm_core(xb, W, As, Bs, rowA, colB, acc);

    const int tid = threadIdx.x, lane = tid & 63, w = tid >> 6;
    const int l15 = lane & 15, lg = lane >> 4;
    const int wr = w >> 1, wc = w & 1;
#pragma unroll
    for (int mi = 0; mi < 4; mi++)
#pragma unroll
        for (int ni = 0; ni < 4; ni++)
#pragma unroll
            for (int rr = 0; rr < 4; rr++) {
                int row = rowA + wr*64 + mi*16 + lg*4 + rr;
                int col = colB + wc*64 + ni*16 + l15;
                C[(size_t)row * 1024 + col] = f2bf(acc[mi][ni][rr]);
            }
    if (nrm) {
        int hh = blockIdx.x * 2 + wc;
#pragma unroll
        for (int mi = 0; mi < 4; mi++)
#pragma unroll
            for (int rr = 0; rr < 4; rr++) {
                float s = 0.f;
#pragma unroll
                for (int ni = 0; ni < 4; ni++) { float v = acc[mi][ni][rr]; s += v * v; }
#pragma unroll
                for (int m = 1; m < 16; m <<= 1) s += __shfl_xor(s, m);
                if (l15 == 0) {
                    int row = rowA + wr*64 + mi*16 + lg*4 + rr;
                    nrm[((size_t)(row >> 11) * 16 + hh) * 2048 + (row & 2047)] = s;
                }
            }
    }
}

// Final projection: fp32 out. 128x64 tile -> grid (16, 32) = 512 blocks (2/CU).
__global__ __launch_bounds__(256) void gemm_out_kernel(
    const u16* __restrict__ ob, const u16* __restrict__ wob, float* __restrict__ out)
{
    __shared__ __align__(16) u16 As[128 * 64];
    __shared__ __align__(16) u16 Bs[64 * 64];
    const int tid = threadIdx.x, lane = tid & 63, w = tid >> 6;
    const int l15 = lane & 15, lg = lane >> 4;
    const int wr = w >> 1, wc = w & 1;
    const int srow = lane >> 3, scol = (lane & 7) * 8;
    const int rowA = blockIdx.y * 128, colB = blockIdx.x * 64;
    constexpr int K = 1024;

    f32x4 acc[4][2] = {};
    for (int kt = 0; kt < 16; ++kt) {
        __syncthreads();
#pragma unroll
        for (int i = 0; i < 4; i++) {
            int r = w * 32 + i * 8;
            gload_lds16(ob + (size_t)(rowA + r + srow) * K + kt * 64 + scol, As + r * 64);
        }
#pragma unroll
        for (int i = 0; i < 2; i++) {
            int r = w * 16 + i * 8;
            gload_lds16(wob + (size_t)(colB + r + srow) * K + kt * 64 + scol, Bs + r * 64);
        }
        __syncthreads();
#pragma unroll
        for (int c = 0; c < 2; c++) {
            short8 af[4], bf[2];
#pragma unroll
            for (int mi = 0; mi < 4; mi++)
                af[mi] = *reinterpret_cast<const short8*>(As + (wr*64 + mi*16 + l15)*64 + c*32 + 8*lg);
#pragma unroll
            for (int ni = 0; ni < 2; ni++)
                bf[ni] = *reinterpret_cast<const short8*>(Bs + (wc*32 + ni*16 + l15)*64 + c*32 + 8*lg);
#pragma unroll
            for (int mi = 0; mi < 4; mi++)
#pragma unroll
                for (int ni = 0; ni < 2; ni++)
                    acc[mi][ni] = __builtin_amdgcn_mfma_f32_16x16x32_bf16(af[mi], bf[ni], acc[mi][ni], 0, 0, 0);
        }
    }
#pragma unroll
    for (int mi = 0; mi < 4; mi++)
#pragma unroll
        for (int ni = 0; ni < 2; ni++)
#pragma unroll
            for (int rr = 0; rr < 4; rr++) {
                int row = rowA + wr*64 + mi*16 + lg*4 + rr;
                int col = colB + wc*32 + ni*16 + l15;
                out[(size_t)row * 1024 + col] = acc[mi][ni][rr];
            }
}

// ---------------------------------------------------------------------------
// V transpose: vb [B*N][D] -> vt [(b*16+h)*64+d][N]  (bf16)
// ---------------------------------------------------------------------------
__global__ __launch_bounds__(256) void transpose_v_kernel(const u16* __restrict__ vb,
                                                          u16* __restrict__ vt)
{
    __shared__ __align__(16) u16 T[64][80];
    const int bid = blockIdx.x;
    const int bh = bid >> 5, tile = bid & 31;
    const int b = bh >> 4, h = bh & 15;
#pragma unroll
    for (int i = 0; i < 2; i++) {
        int flat = threadIdx.x + i * 256;      // 0..511
        int r = flat >> 3, c8 = (flat & 7) * 8;
        short8 v = *reinterpret_cast<const short8*>(
            vb + (size_t)(b * 2048 + tile * 64 + r) * 1024 + h * 64 + c8);
#pragma unroll
        for (int e = 0; e < 8; e++) T[c8 + e][r] = (u16)v[e];
    }
    __syncthreads();
#pragma unroll
    for (int i = 0; i < 2; i++) {
        int flat = threadIdx.x + i * 256;
        int d = flat >> 3, c8 = (flat & 7) * 8;
        short8 v = *reinterpret_cast<const short8*>(&T[d][c8]);
        *reinterpret_cast<short8*>(vt + ((size_t)bh * 64 + d) * 2048 + tile * 64 + c8) = v;
    }
}

// ---------------------------------------------------------------------------
// Fused causal hyperbolic flash attention, fixed-shift softmax (scores <= 0).
// Block = 4 waves; each wave owns TWO 16-row Q groups (32 rows/block);
// KV tiles split t = w mod 4. Software-pipelined: K prefetched 1 iter ahead,
// V hoisted before the distance VALU, PV(g0) overlapped with VALU(g1).
// ---------------------------------------------------------------------------
__global__ __launch_bounds__(256) void hypattn_kernel(
    const u16* __restrict__ qb, const u16* __restrict__ kb, const u16* __restrict__ vt,
    const float* __restrict__ qnp, const float* __restrict__ knp,
    u16* __restrict__ ob, const float* __restrict__ log_c, const float* __restrict__ log_beta)
{
    // union: P staging [4][2][16][72] u16 (18432 B) / epilogue [4][16][68] f32
    __shared__ __align__(16) char smem[4 * 2 * 16 * 72 * 2];
    __shared__ float Pl[4][2][16];
    u16 (*Pw)[2][16][72] = reinterpret_cast<u16 (*)[2][16][72]>(smem);
    float* SUf = reinterpret_cast<float*>(smem);

    const int tid  = threadIdx.x;
    const int w    = tid >> 6;
    const int lane = tid & 63;
    const int l15  = lane & 15;
    const int lg   = lane >> 4;

    // XCD-chunked swizzle (bijective: 2048 = 8*256) + big-tiles-first
    const int swz = (blockIdx.x & 7) * 256 + (blockIdx.x >> 3);
    const int wt  = 2047 - swz;
    const int bh  = wt >> 6;
    const int jj  = wt & 63;
    const int b   = bh >> 4, h = bh & 15;
    const int n0  = jj * 32;
    const int ntiles = (jj >> 1) + 1;

    const float cc   = log1pf(__expf(log_c[0]));
    const float beta = log1pf(__expf(log_beta[0])) + 0.5f;
    const float Aq = -beta * 0.693f * 1.44269504f;
    const float Bl = -beta * 0.5f;
    const float Cn = -beta * 0.25f * cc * 1.44269504f;

    short8 qf[2][2];
#pragma unroll
    for (int g = 0; g < 2; g++) {
        size_t base = ((size_t)(b * 2048 + n0 + g * 16 + l15)) * 1024 + h * 64;
        qf[g][0] = *reinterpret_cast<const short8*>(qb + base + 8 * lg);
        qf[g][1] = *reinterpret_cast<const short8*>(qb + base + 32 + 8 * lg);
    }
    float qnr[2][4];
#pragma unroll
    for (int g = 0; g < 2; g++)
#pragma unroll
        for (int rr = 0; rr < 4; rr++)
            qnr[g][rr] = qnp[(size_t)bh * 2048 + n0 + g * 16 + lg * 4 + rr];

    float psum[2][4] = {};
    f32x4 oacc0[4] = {}, oacc1[4] = {};

    const u16* kbh = kb + (size_t)b * 2048 * 1024 + h * 64;
    const u16* vbh = vt + (size_t)bh * 64 * 2048;
    const float* knb = knp + (size_t)bh * 2048;

    short8 kf[2][4];
#define LOAD_K(TT)                                                              \
    {                                                                           \
      const u16* kt0 = kbh + (size_t)((TT) * 64) * 1024;                        \
      _Pragma("unroll") for (int cch = 0; cch < 2; cch++)                       \
        _Pragma("unroll") for (int nt = 0; nt < 4; nt++)                        \
          kf[cch][nt] = *reinterpret_cast<const short8*>(                       \
              kt0 + (size_t)(nt * 16 + l15) * 1024 + cch * 32 + 8 * lg);        \
    }

// distance -> p = exp2(...), fixed shift m=0 (scores <= 0). Exact fixup +
// causal mask only on the (wave-uniform) diagonal tile.
#define PROC_GROUP(G, SACC)                                                     \
    {                                                                           \
      float p[4][4];                                                            \
      _Pragma("unroll") for (int nt = 0; nt < 4; nt++)                          \
        _Pragma("unroll") for (int rr = 0; rr < 4; rr++) {                      \
          float qk = SACC[nt][rr];                                              \
          float ns = qnr[G][rr] + knj[nt];                                      \
          float d2 = __builtin_fmaf(qk, -2.f, ns);                              \
          float lgv = __builtin_amdgcn_logf(d2);                                \
          p[nt][rr] = __builtin_amdgcn_exp2f(                                   \
              __builtin_fmaf(Bl, lgv, __builtin_fmaf(Cn, ns, Aq)));             \
        }                                                                       \
      if (lastt) {                                                              \
        _Pragma("unroll") for (int nt = 0; nt < 4; nt++)                        \
          _Pragma("unroll") for (int rr = 0; rr < 4; rr++) {                    \
            float qk = SACC[nt][rr];                                            \
            float ns = qnr[G][rr] + knj[nt];                                    \
            float d2v = fmaxf(__builtin_fmaf(qk, -2.f, ns), 0.f);               \
            if (d2v <= 4.0f) {                                                  \
              float ed = __builtin_amdgcn_sqrtf(d2v + 1e-8f);                   \
              float cn = cc * ns;                                               \
              float dist = (ed < 0.1f) ? ed * (1.f + 0.5f*cn + 0.125f*cn*cn)    \
                                       : ed * __builtin_amdgcn_sqrtf(1.f + cn); \
              p[nt][rr] = __expf(-beta * dist);                                 \
            }                                                                   \
            if (t*64 + nt*16 + l15 > n0 + (G)*16 + lg*4 + rr) p[nt][rr] = 0.f;  \
          }                                                                     \
      }                                                                         \
      _Pragma("unroll") for (int nt = 0; nt < 4; nt++)                          \
        _Pragma("unroll") for (int rr = 0; rr < 4; rr++) {                      \
          psum[G][rr] += p[nt][rr];                                             \
          Pw[w][G][lg*4 + rr][nt*16 + l15] = f2bf(p[nt][rr]);                   \
        }                                                                       \
    }

    if (w < ntiles) LOAD_K(w)

    for (int t = w; t < ntiles; t += 4) {
        const bool lastt = (t == ntiles - 1);
        // --- QK^T for both groups (kf already in regs via prefetch) ---
        f32x4 sacc0[4] = {}, sacc1[4] = {};
        __builtin_amdgcn_s_setprio(1);
#pragma unroll
        for (int cch = 0; cch < 2; cch++)
#pragma unroll
            for (int nt = 0; nt < 4; nt++) {
                sacc0[nt] = __builtin_amdgcn_mfma_f32_16x16x32_bf16(qf[0][cch], kf[cch][nt], sacc0[nt], 0, 0, 0);
                sacc1[nt] = __builtin_amdgcn_mfma_f32_16x16x32_bf16(qf[1][cch], kf[cch][nt], sacc1[nt], 0, 0, 0);
            }
        __builtin_amdgcn_s_setprio(0);

        // --- issue V loads now; in flight during the distance VALU ---
        short8 vf[2][4];
        const u16* vt0 = vbh + t * 64;
#pragma unroll
        for (int cch = 0; cch < 2; cch++)
#pragma unroll
            for (int no = 0; no < 4; no++)
                vf[cch][no] = *reinterpret_cast<const short8*>(
                    vt0 + (size_t)(no * 16 + l15) * 2048 + cch * 32 + 8 * lg);

        float knj[4];
#pragma unroll
        for (int nt = 0; nt < 4; nt++) knj[nt] = knb[t * 64 + nt * 16 + l15];

        PROC_GROUP(0, sacc0)

        // --- PV group 0 (MFMA pipe) overlaps VALU of group 1 ---
        __builtin_amdgcn_s_setprio(1);
#pragma unroll
        for (int cch = 0; cch < 2; cch++) {
            short8 pf0 = *reinterpret_cast<const short8*>(&Pw[w][0][l15][cch * 32 + 8 * lg]);
#pragma unroll
            for (int no = 0; no < 4; no++)
                oacc0[no] = __builtin_amdgcn_mfma_f32_16x16x32_bf16(pf0, vf[cch][no], oacc0[no], 0, 0, 0);
        }
        __builtin_amdgcn_s_setprio(0);

        PROC_GROUP(1, sacc1)

        // --- prefetch K for tile t+4; in flight across PV(g1) + next QK ---
        if (t + 4 < ntiles) LOAD_K(t + 4)

        __builtin_amdgcn_s_setprio(1);
#pragma unroll
        for (int cch = 0; cch < 2; cch++) {
            short8 pf1 = *reinterpret_cast<const short8*>(&Pw[w][1][l15][cch * 32 + 8 * lg]);
#pragma unroll
            for (int no = 0; no < 4; no++)
                oacc1[no] = __builtin_amdgcn_mfma_f32_16x16x32_bf16(pf1, vf[cch][no], oacc1[no], 0, 0, 0);
        }
        __builtin_amdgcn_s_setprio(0);
    }
#undef PROC_GROUP
#undef LOAD_K

    // --- psum reduce within 16-lane groups, stash per-wave row sums ---
#pragma unroll
    for (int g = 0; g < 2; g++)
#pragma unroll
        for (int rr = 0; rr < 4; rr++) {
#pragma unroll
            for (int m = 1; m < 16; m <<= 1)
                psum[g][rr] += __shfl_xor(psum[g][rr], m);
        }
    if (l15 == 0) {
#pragma unroll
        for (int g = 0; g < 2; g++)
#pragma unroll
            for (int rr = 0; rr < 4; rr++)
                Pl[w][g][lg * 4 + rr] = psum[g][rr];
    }

#define EPILOG(G, OACC)                                                          \
    __syncthreads();                                                             \
    _Pragma("unroll") for (int no = 0; no < 4; no++)                             \
      _Pragma("unroll") for (int rr = 0; rr < 4; rr++)                           \
        SUf[(w * 16 + lg * 4 + rr) * 68 + no * 16 + l15] = OACC[no][rr];         \
    __syncthreads();                                                             \
    {                                                                            \
      int r = tid >> 4, c4 = (tid & 15) * 4;                                     \
      float4 s = make_float4(0.f, 0.f, 0.f, 0.f); float l = 0.f;                 \
      _Pragma("unroll") for (int w2 = 0; w2 < 4; w2++) {                         \
        const float4 tt = *reinterpret_cast<const float4*>(&SUf[(w2*16+r)*68+c4]);\
        s.x += tt.x; s.y += tt.y; s.z += tt.z; s.w += tt.w;                      \
        l += Pl[w2][G][r];                                                       \
      }                                                                          \
      float inv = 1.f / l;                                                       \
      ushort4 o; o.x = f2bf(s.x*inv); o.y = f2bf(s.y*inv);                       \
      o.z = f2bf(s.z*inv); o.w = f2bf(s.w*inv);                                  \
      *reinterpret_cast<ushort4*>(                                               \
          ob + ((size_t)(b*2048 + n0 + (G)*16 + r))*1024 + h*64 + c4) = o;       \
    }

    EPILOG(0, oacc0)
    __syncthreads();
    EPILOG(1, oacc1)
#undef EPILOG
}

// ---------------------------------------------------------------------------
extern "C" void kernel_launch(void* const* d_in, const int* in_sizes, int n_in,
                              void* d_out, int out_size, void* d_ws, size_t ws_size,
                              hipStream_t stream)
{
    const float* x        = (const float*)d_in[0];
    const float* Wq       = (const float*)d_in[1];
    const float* Wk       = (const float*)d_in[2];
    const float* Wv       = (const float*)d_in[3];
    const float* Wo       = (const float*)d_in[4];
    const float* log_c    = (const float*)d_in[5];
    const float* log_beta = (const float*)d_in[6];
    float* out = (float*)d_out;

    char* ws = (char*)d_ws;
    u16* xb  = (u16*)(ws);
    u16* wqb = (u16*)(ws + ((size_t)8  << 20));
    u16* wkb = (u16*)(ws + ((size_t)10 << 20));
    u16* wvb = (u16*)(ws + ((size_t)12 << 20));
    u16* wob = (u16*)(ws + ((size_t)14 << 20));
    u16* qb  = (u16*)(ws + ((size_t)16 << 20));
    u16* kb  = (u16*)(ws + ((size_t)24 << 20));
    u16* vb  = (u16*)(ws + ((size_t)32 << 20));   // dead after transpose; reused as ob
    u16* vt  = (u16*)(ws + ((size_t)40 << 20));
    float* qn = (float*)(ws + ((size_t)48 << 20));
    float* kn = (float*)(ws + ((size_t)48 << 20) + ((size_t)256 << 10));
    u16* ob = vb;

    castx_kernel<<<4096, 256, 0, stream>>>(x, Wq, Wk, Wv, Wo, xb, wqb, wkb, wvb, wob);
    gemm_qkv_kernel<<<dim3(8, 32, 3), 256, 0, stream>>>(xb, wqb, wkb, wvb, qb, kb, vb, qn, kn);
    transpose_v_kernel<<<1024, 256, 0, stream>>>(vb, vt);
    hypattn_kernel<<<2048, 256, 0, stream>>>(qb, kb, vt, qn, kn, ob, log_c, log_beta);
    gemm_out_kernel<<<dim3(16, 32), 256, 0, stream>>>(ob, wob, out);
}